// Round 7
// baseline (145.426 us; speedup 1.0000x reference)
//
#include <hip/hip_runtime.h>

#define BATCH 50
#define NATOMS 512
#define NBONDS 4096
#define NXF (NATOMS*3)            // floats of x per batch = 1536 (6 KB)
#define ILP 2                     // bonds per thread (independent MLP chains)
#define BPB (NBONDS/(256*ILP))    // bond blocks per batch = 8
#define BITS_W (NATOMS*NATOMS/32) // ownership bitmask words per batch = 8192

__device__ __forceinline__ float sigmoidf_(float x){ return 1.f/(1.f+__expf(-x)); }

// exact transcription of reference _taper
__device__ __forceinline__ float taperf_(float r, float rmin, float rmax){
    float r3  = (r > rmax) ? 1.f : 0.f;
    bool  ok  = (r <= rmax) && (r > rmin);
    float r2  = ok ? r   : 0.f;
    float r20 = ok ? 1.f : 0.f;
    float d   = rmin - rmax;
    float rterm = 1.f/(d*d*d);
    float rm  = rmin*r20;
    float rd  = rm - r2;
    float trm1 = rm + 2.f*r2 - 3.f*rmax*r20;
    return rterm*rd*rd*trm1 + r3;
}

// Fused kernel, ILP=2: each thread computes TWO independent bonds. The MLP
// dependency chain (~600 cy) is the bottleneck at 2 waves/SIMD (204 VGPR);
// two interleaved chains share the preloaded weight registers, doubling
// issue-slots-per-wave for ~30 extra VGPRs. Grid halves to 400 blocks ->
// fully co-resident (no second dispatch round).
// No __threadfence (R6-proven): device-scope atomics + pre-barrier vmcnt
// drain make it redundant; tail reads agent-scope atomic loads.
__global__ __launch_bounds__(256, 2) void fused_kernel(
    const float* __restrict__ x, const float* __restrict__ cell, const float* __restrict__ rcell,
    const float* __restrict__ sp_p, const float* __restrict__ gp, const float* __restrict__ bp,
    const float* __restrict__ fe_wi, const float* __restrict__ fe_w, const float* __restrict__ fe_b,
    const float* __restrict__ fe_wo, const float* __restrict__ fe_bo,
    const int* __restrict__ bdid, const int* __restrict__ spec,
    float* __restrict__ Delta, float* __restrict__ Delta_pi, float* __restrict__ SO,
    float* __restrict__ ebond_acc, unsigned* __restrict__ done, unsigned* __restrict__ bits,
    float* __restrict__ out)
{
    __shared__ float s_x[NXF];                       // 6 KB coordinates
    __shared__ __align__(16) float s_w[320];         // [l][u][v] transposed
    __shared__ __align__(16) float s_wo[8];
    __shared__ float s_wi[24], s_bb[40];
    __shared__ float s_part[4];
    __shared__ unsigned s_rank;
    int tid = threadIdx.x;
    int b   = blockIdx.y;

    // coalesced float4 stage of x[b] into LDS (384 float4 / 256 threads)
    const float4* xb4 = (const float4*)(x + (size_t)b*NXF);
    float4* sx4 = (float4*)s_x;
    sx4[tid] = xb4[tid];
    if(tid < NXF/4 - 256) sx4[tid+256] = xb4[tid+256];
    // weights: transpose [l][v][u] -> [l][u][v] while staging.
    // LOOP, not a single predicate: 320 elements > 256 threads (R3 bug).
    for(int t=tid; t<320; t+=256){
        int l = t>>6, rr = t&63, v = rr>>3, u = rr&7;
        s_w[(l<<6) + (u<<3) + v] = fe_w[t];
    }
    if(tid < 24) s_wi[tid] = fe_wi[tid];
    if(tid < 40) s_bb[tid] = fe_b[tid];
    if(tid < 8)  s_wo[tid] = fe_wo[tid];
    __syncthreads();

    // wave-uniform params -> scalar loads (hoisted once, few values)
    float botol = gp[6];
    float rosi=bp[0], ropi=bp[1], ropp=bp[2];
    float bo1=bp[3], bo2=bp[4], bo3=bp[5], bo4=bp[6], bo5=bp[7], bo6=bp[8], Desi=bp[9];
    float bo_out = fe_bo[0];
    const float* cb = cell  + b*9;
    const float* rb = rcell + b*9;
    float tmax = 2.f*botol;

    int k0 = blockIdx.x*(256*ILP) + tid;     // bond q: k0 + q*256 (coalesced)
    int iA[ILP], jA[ILP];
    float siA[ILP], piA[ILP], ppA[ILP];

    #pragma unroll
    for(int q=0;q<ILP;q++){
        int k = k0 + q*256;
        int2 ij = ((const int2*)bdid)[k];
        int i = ij.x, j = ij.y;
        iA[q]=i; jA[q]=j;
        float dx0 = s_x[3*i+0]-s_x[3*j+0];
        float dx1 = s_x[3*i+1]-s_x[3*j+1];
        float dx2 = s_x[3*i+2]-s_x[3*j+2];
        // fractional coords, minimum image, back to cartesian
        float f0 = dx0*rb[0]+dx1*rb[3]+dx2*rb[6];
        float f1 = dx0*rb[1]+dx1*rb[4]+dx2*rb[7];
        float f2 = dx0*rb[2]+dx1*rb[5]+dx2*rb[8];
        f0 = (f0>0.5f)?f0-1.f:f0; f0 = (f0<-0.5f)?f0+1.f:f0;
        f1 = (f1>0.5f)?f1-1.f:f1; f1 = (f1<-0.5f)?f1+1.f:f1;
        f2 = (f2>0.5f)?f2-1.f:f2; f2 = (f2<-0.5f)?f2+1.f:f2;
        float v0 = f0*cb[0]+f1*cb[3]+f2*cb[6];
        float v1 = f0*cb[1]+f1*cb[4]+f2*cb[7];
        float v2 = f0*cb[2]+f1*cb[5]+f2*cb[8];
        float r = sqrtf(v0*v0+v1*v1+v2*v2);

        float eterm1 = (1.f+botol)*__expf(bo1*__powf(r/rosi, bo2));
        float eterm2 = __expf(bo3*__powf(r/ropi, bo4));
        float eterm3 = __expf(bo5*__powf(r/ropp, bo6));
        siA[q] = taperf_(eterm1, botol, tmax)*(eterm1-botol);
        piA[q] = taperf_(eterm2, botol, tmax)*eterm2;
        ppA[q] = taperf_(eterm3, botol, tmax)*eterm3;
    }

    // ---- MLP x2, interleaved: weights shared across the two chains ----
    float o[ILP][8];
    #pragma unroll
    for(int q=0;q<ILP;q++)
        #pragma unroll
        for(int u=0;u<8;u++)
            o[q][u] = sigmoidf_(siA[q]*s_wi[u] + piA[q]*s_wi[8+u] + ppA[q]*s_wi[16+u]);
    #pragma unroll
    for(int l=0;l<5;l++){
        const float4* wl = (const float4*)(s_w + (l<<6));
        const float*  bl = s_bb + (l<<3);
        float no[ILP][8];
        #pragma unroll
        for(int u=0;u<8;u++){
            float4 wa = wl[2*u], wb = wl[2*u+1];      // uniform ds_read_b128 x2, shared by both chains
            #pragma unroll
            for(int q=0;q<ILP;q++){
                float a0 = fmaf(o[q][0],wa.x, bl[u]);
                float a1 = o[q][1]*wa.y;
                a0 = fmaf(o[q][2],wa.z,a0); a1 = fmaf(o[q][3],wa.w,a1);
                a0 = fmaf(o[q][4],wb.x,a0); a1 = fmaf(o[q][5],wb.y,a1);
                a0 = fmaf(o[q][6],wb.z,a0); a1 = fmaf(o[q][7],wb.w,a1);
                no[q][u] = sigmoidf_(a0+a1);
            }
        }
        #pragma unroll
        for(int q=0;q<ILP;q++)
            #pragma unroll
            for(int u=0;u<8;u++) o[q][u]=no[q][u];
    }
    float4 woa = ((const float4*)s_wo)[0], wob = ((const float4*)s_wo)[1];
    float esum = 0.f;
    #pragma unroll
    for(int q=0;q<ILP;q++){
        float a0 = fmaf(o[q][0],woa.x, bo_out);
        float a1 = o[q][1]*woa.y;
        a0 = fmaf(o[q][2],woa.z,a0); a1 = fmaf(o[q][3],woa.w,a1);
        a0 = fmaf(o[q][4],wob.x,a0); a1 = fmaf(o[q][5],wob.y,a1);
        a0 = fmaf(o[q][6],wob.z,a0); a1 = fmaf(o[q][7],wob.w,a1);
        esum += sigmoidf_(a0+a1);
    }

    // per-atom scatter: first arrival on the (b,i,j) bit owns the pair
    #pragma unroll
    for(int q=0;q<ILP;q++){
        int i=iA[q], j=jA[q];
        unsigned pidx = (unsigned)(i*NATOMS + j);
        unsigned old = atomicOr(&bits[(size_t)b*BITS_W + (pidx>>5)], 1u<<(pidx&31));
        if(((old>>(pidx&31)) & 1u) == 0u){
            float bop = siA[q]+piA[q]+ppA[q];
            float dpi = piA[q]+ppA[q];
            float* Db = Delta    + (size_t)b*NATOMS;
            float* Pb = Delta_pi + (size_t)b*NATOMS;
            float* Sb = SO       + (size_t)b*NATOMS;
            atomicAdd(&Db[i], bop); atomicAdd(&Db[j], bop);
            atomicAdd(&Pb[i], dpi); atomicAdd(&Pb[j], dpi);
            atomicAdd(&Sb[i], siA[q]); atomicAdd(&Sb[j], siA[q]);
        }
    }

    // ebond partial: sum over ALL bonds (duplicates included)
    float ev = -Desi*esum;
    #pragma unroll
    for(int o2=32;o2>0;o2>>=1) ev += __shfl_down(ev, o2, 64);
    if((tid & 63) == 0) s_part[tid>>6] = ev;
    __syncthreads();
    if(tid==0) atomicAdd(&ebond_acc[b], s_part[0]+s_part[1]+s_part[2]+s_part[3]);

    // take a completion ticket for batch b. The barrier above drained this
    // block's vmcnt -> all its device-scope atomics are performed. No fence.
    __syncthreads();
    if(tid==0) s_rank = atomicAdd(&done[b], 1u);
    __syncthreads();
    if(s_rank != BPB-1) return;

    // ---- tail block (last to finish for this batch): atom phase ----
    float lp1=gp[0], ovun3=gp[1], ovun4=gp[2], ovun6=gp[3], ovun7=gp[4], ovun8=gp[5];
    float acc = 0.f;
    for(int n=tid; n<NATOMS; n+=256){
        int s = spec[n];
        const float* pa = sp_p + s*5;
        float val=pa[0], vale=pa[1], lp2=pa[2], ovun2=pa[3], ovun5=pa[4];
        size_t idx = (size_t)b*NATOMS + n;
        // agent-scope atomic loads: read through the coherent point, no stale L1
        float D   = __hip_atomic_load(&Delta[idx],    __ATOMIC_RELAXED, __HIP_MEMORY_SCOPE_AGENT);
        float Dpi = __hip_atomic_load(&Delta_pi[idx], __ATOMIC_RELAXED, __HIP_MEMORY_SCOPE_AGENT);
        float so  = __hip_atomic_load(&SO[idx],       __ATOMIC_RELAXED, __HIP_MEMORY_SCOPE_AGENT);

        float Nlp = 0.5f*(vale-val);
        float de  = 0.5f*(D-vale);
        float De  = fminf(ceilf(de), 0.f);          // -relu(-ceil(x)) == min(ceil(x),0)
        float t   = 1.f + de - De;
        float nlp = -De + __expf(-lp1*4.f*t*t);
        float Dlp = fmaxf(Nlp - nlp + 1.f, 0.f) - 1.f;
        float Elone = lp2*Dlp/(1.f+__expf(-75.f*Dlp));
        float dlp = D - val - Dlp/(1.f + ovun3*__expf(ovun4*Dpi));
        float denom = dlp + val;
        float otrm1 = 1.f/((denom!=0.f)?denom:1e-8f);
        float Eover = so*otrm1*dlp*sigmoidf_(-ovun2*dlp);
        float Eunder = -ovun5*(1.f-__expf(ovun6*dlp))*sigmoidf_(ovun2*dlp)
                       /(1.f + ovun7*__expf(ovun8*Dpi));
        acc += Elone + Eover + Eunder;
    }
    #pragma unroll
    for(int o2=32;o2>0;o2>>=1) acc += __shfl_down(acc, o2, 64);
    __syncthreads();                          // s_part reuse
    if((tid & 63) == 0) s_part[tid>>6] = acc;
    __syncthreads();
    if(tid==0){
        float eb = __hip_atomic_load(&ebond_acc[b], __ATOMIC_RELAXED, __HIP_MEMORY_SCOPE_AGENT);
        out[b] = eb + s_part[0]+s_part[1]+s_part[2]+s_part[3];   // sole writer
    }
}

extern "C" void kernel_launch(void* const* d_in, const int* in_sizes, int n_in,
                              void* d_out, int out_size, void* d_ws, size_t ws_size,
                              hipStream_t stream)
{
    const float* x     = (const float*)d_in[0];
    const float* cell  = (const float*)d_in[1];
    const float* rcell = (const float*)d_in[2];
    const float* sp_p  = (const float*)d_in[3];
    const float* gp    = (const float*)d_in[4];
    const float* bp    = (const float*)d_in[5];
    const float* fe_wi = (const float*)d_in[6];
    const float* fe_w  = (const float*)d_in[7];
    const float* fe_b  = (const float*)d_in[8];
    const float* fe_wo = (const float*)d_in[9];
    const float* fe_bo = (const float*)d_in[10];
    const int*   bdid  = (const int*)d_in[11];
    const int*   spec  = (const int*)d_in[12];
    float* out = (float*)d_out;

    // ws layout (contiguous, one memset):
    // Delta | Delta_pi | SO | ebond_acc | done | ownership bits
    float* Delta     = (float*)d_ws;
    float* Delta_pi  = Delta + BATCH*NATOMS;
    float* SO        = Delta_pi + BATCH*NATOMS;
    float* ebond_acc = SO + BATCH*NATOMS;
    unsigned* done   = (unsigned*)(ebond_acc + BATCH);
    unsigned* bits   = done + BATCH;

    size_t zbytes = (size_t)(3*BATCH*NATOMS + BATCH)*sizeof(float)
                  + (size_t)BATCH*sizeof(unsigned)
                  + (size_t)BATCH*BITS_W*sizeof(unsigned);
    hipMemsetAsync(d_ws, 0, zbytes, stream);

    fused_kernel<<<dim3(BPB, BATCH), 256, 0, stream>>>(
        x, cell, rcell, sp_p, gp, bp, fe_wi, fe_w, fe_b, fe_wo, fe_bo,
        bdid, spec, Delta, Delta_pi, SO, ebond_acc, done, bits, out);
}

// Round 8
// 117.444 us; speedup vs baseline: 1.2383x; 1.2383x over previous
//
#include <hip/hip_runtime.h>

#define BATCH 50
#define NATOMS 512
#define NBONDS 4096
#define NXF (NATOMS*3)            // floats of x per batch = 1536 (6 KB)
#define ILP 4                     // bonds per thread
#define BPB (NBONDS/(256*ILP))    // bond blocks per batch = 4
#define BITS_W (NATOMS*NATOMS/32) // pair bitmask words, SINGLE copy (batch-independent)

__device__ __forceinline__ float sigmoidf_(float x){ return 1.f/(1.f+__expf(-x)); }

// exact transcription of reference _taper
__device__ __forceinline__ float taperf_(float r, float rmin, float rmax){
    float r3  = (r > rmax) ? 1.f : 0.f;
    bool  ok  = (r <= rmax) && (r > rmin);
    float r2  = ok ? r   : 0.f;
    float r20 = ok ? 1.f : 0.f;
    float d   = rmin - rmax;
    float rterm = 1.f/(d*d*d);
    float rm  = rmin*r20;
    float rd  = rm - r2;
    float trm1 = rm + 2.f*r2 - 3.f*rmax*r20;
    return rterm*rd*rd*trm1 + r3;
}

// Ownership is BATCH-INDEPENDENT (bdid shared by all 50 batches): claim once,
// emit ownerf[k] in {0,1}. Exactly one duplicate of each (i,j) pair wins;
// duplicates carry bit-identical bond values so count-once is exact.
__global__ __launch_bounds__(256) void claim_kernel(const int* __restrict__ bdid,
                                                    unsigned* __restrict__ bits,
                                                    float* __restrict__ ownerf){
    int k = blockIdx.x*256 + threadIdx.x;
    int2 ij = ((const int2*)bdid)[k];
    unsigned pidx = (unsigned)(ij.x*NATOMS + ij.y);
    unsigned old = atomicOr(&bits[pidx>>5], 1u<<(pidx&31));
    ownerf[k] = ((old>>(pidx&31)) & 1u) ? 0.f : 1.f;
}

// Fused bond+tail kernel, ILP=4, LDS pre-aggregation:
//  - per-atom scatter goes to __shared__ accumulators (ds_add_f32,
//    fire-and-forget, on-CU) scaled by ownerf[k] -> no global atomic and no
//    latency-dependent branch in the hot loop;
//  - one flush per block: 512 atoms x 3 arrays / 256 threads = 6 global
//    atomicAdds per thread (4x fewer global atomics than per-bond scatter);
//  - no __threadfence (R6-proven): device-scope atomics + pre-barrier vmcnt
//    drain; tail block reads with agent-scope atomic loads.
__global__ __launch_bounds__(256) void fused_kernel(
    const float* __restrict__ x, const float* __restrict__ cell, const float* __restrict__ rcell,
    const float* __restrict__ sp_p, const float* __restrict__ gp, const float* __restrict__ bp,
    const float* __restrict__ fe_wi, const float* __restrict__ fe_w, const float* __restrict__ fe_b,
    const float* __restrict__ fe_wo, const float* __restrict__ fe_bo,
    const int* __restrict__ bdid, const int* __restrict__ spec,
    const float* __restrict__ ownerf,
    float* __restrict__ Delta, float* __restrict__ Delta_pi, float* __restrict__ SO,
    float* __restrict__ ebond_acc, unsigned* __restrict__ done,
    float* __restrict__ out)
{
    __shared__ float s_x[NXF];                       // 6 KB coordinates
    __shared__ float accD[NATOMS], accP[NATOMS], accS[NATOMS]; // 6 KB LDS accumulators
    __shared__ __align__(16) float s_w[320];         // [l][u][v] transposed
    __shared__ __align__(16) float s_wo[8];
    __shared__ float s_wi[24], s_bb[40];
    __shared__ float s_part[4];
    __shared__ unsigned s_rank;
    int tid = threadIdx.x;
    int b   = blockIdx.y;

    // coalesced float4 stage of x[b] into LDS (384 float4 / 256 threads)
    const float4* xb4 = (const float4*)(x + (size_t)b*NXF);
    float4* sx4 = (float4*)s_x;
    sx4[tid] = xb4[tid];
    if(tid < NXF/4 - 256) sx4[tid+256] = xb4[tid+256];
    // zero LDS accumulators
    for(int n=tid; n<NATOMS; n+=256){ accD[n]=0.f; accP[n]=0.f; accS[n]=0.f; }
    // weights: transpose [l][v][u] -> [l][u][v] while staging (LOOP: 320>256)
    for(int t=tid; t<320; t+=256){
        int l = t>>6, rr = t&63, v = rr>>3, u = rr&7;
        s_w[(l<<6) + (u<<3) + v] = fe_w[t];
    }
    if(tid < 24) s_wi[tid] = fe_wi[tid];
    if(tid < 40) s_bb[tid] = fe_b[tid];
    if(tid < 8)  s_wo[tid] = fe_wo[tid];
    __syncthreads();

    // wave-uniform params -> scalar loads
    float botol = gp[6];
    float rosi=bp[0], ropi=bp[1], ropp=bp[2];
    float bo1=bp[3], bo2=bp[4], bo3=bp[5], bo4=bp[6], bo5=bp[7], bo6=bp[8], Desi=bp[9];
    float bo_out = fe_bo[0];
    const float* cb = cell  + b*9;
    const float* rb = rcell + b*9;
    float tmax = 2.f*botol;

    int kbase = blockIdx.x*(256*ILP) + tid;
    float o[ILP][8];

    // ---- per-bond: geometry -> LDS scatter -> MLP layer 0 ----
    // (si/pi/pp/i/j consumed inside the iteration; only o[q][8] crosses)
    #pragma unroll
    for(int q=0;q<ILP;q++){
        int k = kbase + q*256;
        float own = ownerf[k];                 // plain load, no branch
        int2 ij = ((const int2*)bdid)[k];
        int i = ij.x, j = ij.y;
        float dx0 = s_x[3*i+0]-s_x[3*j+0];
        float dx1 = s_x[3*i+1]-s_x[3*j+1];
        float dx2 = s_x[3*i+2]-s_x[3*j+2];
        float f0 = dx0*rb[0]+dx1*rb[3]+dx2*rb[6];
        float f1 = dx0*rb[1]+dx1*rb[4]+dx2*rb[7];
        float f2 = dx0*rb[2]+dx1*rb[5]+dx2*rb[8];
        f0 = (f0>0.5f)?f0-1.f:f0; f0 = (f0<-0.5f)?f0+1.f:f0;
        f1 = (f1>0.5f)?f1-1.f:f1; f1 = (f1<-0.5f)?f1+1.f:f1;
        f2 = (f2>0.5f)?f2-1.f:f2; f2 = (f2<-0.5f)?f2+1.f:f2;
        float v0 = f0*cb[0]+f1*cb[3]+f2*cb[6];
        float v1 = f0*cb[1]+f1*cb[4]+f2*cb[7];
        float v2 = f0*cb[2]+f1*cb[5]+f2*cb[8];
        float r = sqrtf(v0*v0+v1*v1+v2*v2);

        float eterm1 = (1.f+botol)*__expf(bo1*__powf(r/rosi, bo2));
        float eterm2 = __expf(bo3*__powf(r/ropi, bo4));
        float eterm3 = __expf(bo5*__powf(r/ropp, bo6));
        float si = taperf_(eterm1, botol, tmax)*(eterm1-botol);
        float pi = taperf_(eterm2, botol, tmax)*eterm2;
        float pp = taperf_(eterm3, botol, tmax)*eterm3;

        // LDS scatter, scaled by ownership (0 adds are harmless)
        float bop = own*(si+pi+pp), dpi = own*(pi+pp), osi = own*si;
        atomicAdd(&accD[i], bop); atomicAdd(&accD[j], bop);
        atomicAdd(&accP[i], dpi); atomicAdd(&accP[j], dpi);
        atomicAdd(&accS[i], osi); atomicAdd(&accS[j], osi);

        // MLP input layer
        #pragma unroll
        for(int u=0;u<8;u++)
            o[q][u] = sigmoidf_(si*s_wi[u] + pi*s_wi[8+u] + pp*s_wi[16+u]);
    }

    // ---- MLP hidden layers, 4 chains interleaved, weights shared ----
    #pragma unroll
    for(int l=0;l<5;l++){
        const float4* wl = (const float4*)(s_w + (l<<6));
        const float*  bl = s_bb + (l<<3);
        float no[ILP][8];
        #pragma unroll
        for(int u=0;u<8;u++){
            float4 wa = wl[2*u], wb = wl[2*u+1];  // uniform ds_read_b128 x2
            #pragma unroll
            for(int q=0;q<ILP;q++){
                float a0 = fmaf(o[q][0],wa.x, bl[u]);
                float a1 = o[q][1]*wa.y;
                a0 = fmaf(o[q][2],wa.z,a0); a1 = fmaf(o[q][3],wa.w,a1);
                a0 = fmaf(o[q][4],wb.x,a0); a1 = fmaf(o[q][5],wb.y,a1);
                a0 = fmaf(o[q][6],wb.z,a0); a1 = fmaf(o[q][7],wb.w,a1);
                no[q][u] = sigmoidf_(a0+a1);
            }
        }
        #pragma unroll
        for(int q=0;q<ILP;q++)
            #pragma unroll
            for(int u=0;u<8;u++) o[q][u]=no[q][u];
    }
    float4 woa = ((const float4*)s_wo)[0], wob = ((const float4*)s_wo)[1];
    float esum = 0.f;
    #pragma unroll
    for(int q=0;q<ILP;q++){
        float a0 = fmaf(o[q][0],woa.x, bo_out);
        float a1 = o[q][1]*woa.y;
        a0 = fmaf(o[q][2],woa.z,a0); a1 = fmaf(o[q][3],woa.w,a1);
        a0 = fmaf(o[q][4],wob.x,a0); a1 = fmaf(o[q][5],wob.y,a1);
        a0 = fmaf(o[q][6],wob.z,a0); a1 = fmaf(o[q][7],wob.w,a1);
        esum += sigmoidf_(a0+a1);
    }

    // ebond partial: sum over ALL bonds (duplicates included)
    float ev = -Desi*esum;
    #pragma unroll
    for(int o2=32;o2>0;o2>>=1) ev += __shfl_down(ev, o2, 64);
    if((tid & 63) == 0) s_part[tid>>6] = ev;
    __syncthreads();   // also completes all LDS accumulator adds (lgkmcnt)
    if(tid==0) atomicAdd(&ebond_acc[b], s_part[0]+s_part[1]+s_part[2]+s_part[3]);

    // flush LDS accumulators -> global (6 atomics/thread instead of 6/bond)
    float* Db = Delta    + (size_t)b*NATOMS;
    float* Pb = Delta_pi + (size_t)b*NATOMS;
    float* Sb = SO       + (size_t)b*NATOMS;
    for(int n=tid; n<NATOMS; n+=256){
        atomicAdd(&Db[n], accD[n]);
        atomicAdd(&Pb[n], accP[n]);
        atomicAdd(&Sb[n], accS[n]);
    }

    // ticket: barrier drains this block's vmcnt -> all its device-scope
    // atomics performed. No fence (R6-proven).
    __syncthreads();
    if(tid==0) s_rank = atomicAdd(&done[b], 1u);
    __syncthreads();
    if(s_rank != BPB-1) return;

    // ---- tail block (last to finish for this batch): atom phase ----
    float lp1=gp[0], ovun3=gp[1], ovun4=gp[2], ovun6=gp[3], ovun7=gp[4], ovun8=gp[5];
    float acc = 0.f;
    for(int n=tid; n<NATOMS; n+=256){
        int s = spec[n];
        const float* pa = sp_p + s*5;
        float val=pa[0], vale=pa[1], lp2=pa[2], ovun2=pa[3], ovun5=pa[4];
        size_t idx = (size_t)b*NATOMS + n;
        float D   = __hip_atomic_load(&Delta[idx],    __ATOMIC_RELAXED, __HIP_MEMORY_SCOPE_AGENT);
        float Dpi = __hip_atomic_load(&Delta_pi[idx], __ATOMIC_RELAXED, __HIP_MEMORY_SCOPE_AGENT);
        float so  = __hip_atomic_load(&SO[idx],       __ATOMIC_RELAXED, __HIP_MEMORY_SCOPE_AGENT);

        float Nlp = 0.5f*(vale-val);
        float de  = 0.5f*(D-vale);
        float De  = fminf(ceilf(de), 0.f);          // -relu(-ceil(x)) == min(ceil(x),0)
        float t   = 1.f + de - De;
        float nlp = -De + __expf(-lp1*4.f*t*t);
        float Dlp = fmaxf(Nlp - nlp + 1.f, 0.f) - 1.f;
        float Elone = lp2*Dlp/(1.f+__expf(-75.f*Dlp));
        float dlp = D - val - Dlp/(1.f + ovun3*__expf(ovun4*Dpi));
        float denom = dlp + val;
        float otrm1 = 1.f/((denom!=0.f)?denom:1e-8f);
        float Eover = so*otrm1*dlp*sigmoidf_(-ovun2*dlp);
        float Eunder = -ovun5*(1.f-__expf(ovun6*dlp))*sigmoidf_(ovun2*dlp)
                       /(1.f + ovun7*__expf(ovun8*Dpi));
        acc += Elone + Eover + Eunder;
    }
    #pragma unroll
    for(int o2=32;o2>0;o2>>=1) acc += __shfl_down(acc, o2, 64);
    __syncthreads();                          // s_part reuse
    if((tid & 63) == 0) s_part[tid>>6] = acc;
    __syncthreads();
    if(tid==0){
        float eb = __hip_atomic_load(&ebond_acc[b], __ATOMIC_RELAXED, __HIP_MEMORY_SCOPE_AGENT);
        out[b] = eb + s_part[0]+s_part[1]+s_part[2]+s_part[3];   // sole writer
    }
}

extern "C" void kernel_launch(void* const* d_in, const int* in_sizes, int n_in,
                              void* d_out, int out_size, void* d_ws, size_t ws_size,
                              hipStream_t stream)
{
    const float* x     = (const float*)d_in[0];
    const float* cell  = (const float*)d_in[1];
    const float* rcell = (const float*)d_in[2];
    const float* sp_p  = (const float*)d_in[3];
    const float* gp    = (const float*)d_in[4];
    const float* bp    = (const float*)d_in[5];
    const float* fe_wi = (const float*)d_in[6];
    const float* fe_w  = (const float*)d_in[7];
    const float* fe_b  = (const float*)d_in[8];
    const float* fe_wo = (const float*)d_in[9];
    const float* fe_bo = (const float*)d_in[10];
    const int*   bdid  = (const int*)d_in[11];
    const int*   spec  = (const int*)d_in[12];
    float* out = (float*)d_out;

    // ws layout (zeroed region first, then ownerf which is overwritten):
    // Delta | Delta_pi | SO | ebond_acc | done | bits | ownerf
    float* Delta     = (float*)d_ws;
    float* Delta_pi  = Delta + BATCH*NATOMS;
    float* SO        = Delta_pi + BATCH*NATOMS;
    float* ebond_acc = SO + BATCH*NATOMS;
    unsigned* done   = (unsigned*)(ebond_acc + BATCH);
    unsigned* bits   = done + BATCH;          // BITS_W words (32 KB), single copy
    float* ownerf    = (float*)(bits + BITS_W);

    size_t zbytes = (size_t)(3*BATCH*NATOMS + BATCH)*sizeof(float)
                  + (size_t)BATCH*sizeof(unsigned)
                  + (size_t)BITS_W*sizeof(unsigned);
    hipMemsetAsync(d_ws, 0, zbytes, stream);
    hipMemsetAsync(out, 0, BATCH*sizeof(float), stream);

    claim_kernel<<<dim3(NBONDS/256), 256, 0, stream>>>(bdid, bits, ownerf);
    fused_kernel<<<dim3(BPB, BATCH), 256, 0, stream>>>(
        x, cell, rcell, sp_p, gp, bp, fe_wi, fe_w, fe_b, fe_wo, fe_bo,
        bdid, spec, ownerf, Delta, Delta_pi, SO, ebond_acc, done, out);
}

// Round 9
// 111.852 us; speedup vs baseline: 1.3002x; 1.0500x over previous
//
#include <hip/hip_runtime.h>

#define BATCH 50
#define NATOMS 512
#define NBONDS 4096
#define NXF (NATOMS*3)            // floats of x per batch = 1536 (6 KB)
#define ILP 2                     // bonds per thread (independent MLP chains)
#define BPB (NBONDS/(256*ILP))    // bond blocks per batch = 8
#define BITS_W (NATOMS*NATOMS/32) // pair bitmask words, SINGLE copy (batch-independent)

__device__ __forceinline__ float sigmoidf_(float x){ return 1.f/(1.f+__expf(-x)); }

// exact transcription of reference _taper
__device__ __forceinline__ float taperf_(float r, float rmin, float rmax){
    float r3  = (r > rmax) ? 1.f : 0.f;
    bool  ok  = (r <= rmax) && (r > rmin);
    float r2  = ok ? r   : 0.f;
    float r20 = ok ? 1.f : 0.f;
    float d   = rmin - rmax;
    float rterm = 1.f/(d*d*d);
    float rm  = rmin*r20;
    float rd  = rm - r2;
    float trm1 = rm + 2.f*r2 - 3.f*rmax*r20;
    return rterm*rd*rd*trm1 + r3;
}

// Ownership is BATCH-INDEPENDENT (bdid shared by all 50 batches): claim once,
// emit ownerf[k] in {0,1}. Exactly one duplicate of each (i,j) pair wins;
// duplicates carry bit-identical bond values so count-once is exact.
__global__ __launch_bounds__(256) void claim_kernel(const int* __restrict__ bdid,
                                                    unsigned* __restrict__ bits,
                                                    float* __restrict__ ownerf){
    int k = blockIdx.x*256 + threadIdx.x;
    int2 ij = ((const int2*)bdid)[k];
    unsigned pidx = (unsigned)(ij.x*NATOMS + ij.y);
    unsigned old = atomicOr(&bits[pidx>>5], 1u<<(pidx&31));
    ownerf[k] = ((old>>(pidx&31)) & 1u) ? 0.f : 1.f;
}

// Fused bond+tail kernel. ILP=2 (R8's ILP=4 forced thin codegen, 60 VGPR,
// serialized weight ds_reads; R5 proved fat 204-VGPR codegen at ILP=1).
// 400 blocks -> 2 blocks/CU -> 2 waves/SIMD x 2 chains = 4 concurrent MLP
// chains per SIMD. LDS pre-aggregation (R8-proven: hbm 34->2.5 MB) kept.
// No __threadfence (R6-proven). Plain launch_bounds: the min-waves arg
// triggered spilling allocations twice (R1, R7) - never again.
__global__ __launch_bounds__(256) void fused_kernel(
    const float* __restrict__ x, const float* __restrict__ cell, const float* __restrict__ rcell,
    const float* __restrict__ sp_p, const float* __restrict__ gp, const float* __restrict__ bp,
    const float* __restrict__ fe_wi, const float* __restrict__ fe_w, const float* __restrict__ fe_b,
    const float* __restrict__ fe_wo, const float* __restrict__ fe_bo,
    const int* __restrict__ bdid, const int* __restrict__ spec,
    const float* __restrict__ ownerf,
    float* __restrict__ Delta, float* __restrict__ Delta_pi, float* __restrict__ SO,
    float* __restrict__ ebond_acc, unsigned* __restrict__ done,
    float* __restrict__ out)
{
    __shared__ float s_x[NXF];                       // 6 KB coordinates
    __shared__ float accD[NATOMS], accP[NATOMS], accS[NATOMS]; // 6 KB LDS accumulators
    __shared__ __align__(16) float s_w[320];         // [l][u][v] transposed
    __shared__ __align__(16) float s_wo[8];
    __shared__ float s_wi[24], s_bb[40];
    __shared__ float s_part[4];
    __shared__ unsigned s_rank;
    int tid = threadIdx.x;
    int b   = blockIdx.y;

    // coalesced float4 stage of x[b] into LDS (384 float4 / 256 threads)
    const float4* xb4 = (const float4*)(x + (size_t)b*NXF);
    float4* sx4 = (float4*)s_x;
    sx4[tid] = xb4[tid];
    if(tid < NXF/4 - 256) sx4[tid+256] = xb4[tid+256];
    // zero LDS accumulators
    for(int n=tid; n<NATOMS; n+=256){ accD[n]=0.f; accP[n]=0.f; accS[n]=0.f; }
    // weights: transpose [l][v][u] -> [l][u][v] while staging (LOOP: 320>256)
    for(int t=tid; t<320; t+=256){
        int l = t>>6, rr = t&63, v = rr>>3, u = rr&7;
        s_w[(l<<6) + (u<<3) + v] = fe_w[t];
    }
    if(tid < 24) s_wi[tid] = fe_wi[tid];
    if(tid < 40) s_bb[tid] = fe_b[tid];
    if(tid < 8)  s_wo[tid] = fe_wo[tid];
    __syncthreads();

    // wave-uniform params -> scalar loads
    float botol = gp[6];
    float rosi=bp[0], ropi=bp[1], ropp=bp[2];
    float bo1=bp[3], bo2=bp[4], bo3=bp[5], bo4=bp[6], bo5=bp[7], bo6=bp[8], Desi=bp[9];
    float bo_out = fe_bo[0];
    const float* cb = cell  + b*9;
    const float* rb = rcell + b*9;
    float tmax = 2.f*botol;

    int kbase = blockIdx.x*(256*ILP) + tid;
    float o[ILP][8];

    // ---- per-bond: geometry -> LDS scatter -> MLP layer 0 ----
    #pragma unroll
    for(int q=0;q<ILP;q++){
        int k = kbase + q*256;
        float own = ownerf[k];                 // plain load, no branch
        int2 ij = ((const int2*)bdid)[k];
        int i = ij.x, j = ij.y;
        float dx0 = s_x[3*i+0]-s_x[3*j+0];
        float dx1 = s_x[3*i+1]-s_x[3*j+1];
        float dx2 = s_x[3*i+2]-s_x[3*j+2];
        float f0 = dx0*rb[0]+dx1*rb[3]+dx2*rb[6];
        float f1 = dx0*rb[1]+dx1*rb[4]+dx2*rb[7];
        float f2 = dx0*rb[2]+dx1*rb[5]+dx2*rb[8];
        f0 = (f0>0.5f)?f0-1.f:f0; f0 = (f0<-0.5f)?f0+1.f:f0;
        f1 = (f1>0.5f)?f1-1.f:f1; f1 = (f1<-0.5f)?f1+1.f:f1;
        f2 = (f2>0.5f)?f2-1.f:f2; f2 = (f2<-0.5f)?f2+1.f:f2;
        float v0 = f0*cb[0]+f1*cb[3]+f2*cb[6];
        float v1 = f0*cb[1]+f1*cb[4]+f2*cb[7];
        float v2 = f0*cb[2]+f1*cb[5]+f2*cb[8];
        float r = sqrtf(v0*v0+v1*v1+v2*v2);

        float eterm1 = (1.f+botol)*__expf(bo1*__powf(r/rosi, bo2));
        float eterm2 = __expf(bo3*__powf(r/ropi, bo4));
        float eterm3 = __expf(bo5*__powf(r/ropp, bo6));
        float si = taperf_(eterm1, botol, tmax)*(eterm1-botol);
        float pi = taperf_(eterm2, botol, tmax)*eterm2;
        float pp = taperf_(eterm3, botol, tmax)*eterm3;

        // LDS scatter, scaled by ownership (0 adds are harmless)
        float bop = own*(si+pi+pp), dpi = own*(pi+pp), osi = own*si;
        atomicAdd(&accD[i], bop); atomicAdd(&accD[j], bop);
        atomicAdd(&accP[i], dpi); atomicAdd(&accP[j], dpi);
        atomicAdd(&accS[i], osi); atomicAdd(&accS[j], osi);

        // MLP input layer
        #pragma unroll
        for(int u=0;u<8;u++)
            o[q][u] = sigmoidf_(si*s_wi[u] + pi*s_wi[8+u] + pp*s_wi[16+u]);
    }

    // ---- MLP hidden layers, 2 chains interleaved, weights shared ----
    #pragma unroll
    for(int l=0;l<5;l++){
        const float4* wl = (const float4*)(s_w + (l<<6));
        const float*  bl = s_bb + (l<<3);
        float no[ILP][8];
        #pragma unroll
        for(int u=0;u<8;u++){
            float4 wa = wl[2*u], wb = wl[2*u+1];  // uniform ds_read_b128 x2
            #pragma unroll
            for(int q=0;q<ILP;q++){
                float a0 = fmaf(o[q][0],wa.x, bl[u]);
                float a1 = o[q][1]*wa.y;
                a0 = fmaf(o[q][2],wa.z,a0); a1 = fmaf(o[q][3],wa.w,a1);
                a0 = fmaf(o[q][4],wb.x,a0); a1 = fmaf(o[q][5],wb.y,a1);
                a0 = fmaf(o[q][6],wb.z,a0); a1 = fmaf(o[q][7],wb.w,a1);
                no[q][u] = sigmoidf_(a0+a1);
            }
        }
        #pragma unroll
        for(int q=0;q<ILP;q++)
            #pragma unroll
            for(int u=0;u<8;u++) o[q][u]=no[q][u];
    }
    float4 woa = ((const float4*)s_wo)[0], wob = ((const float4*)s_wo)[1];
    float esum = 0.f;
    #pragma unroll
    for(int q=0;q<ILP;q++){
        float a0 = fmaf(o[q][0],woa.x, bo_out);
        float a1 = o[q][1]*woa.y;
        a0 = fmaf(o[q][2],woa.z,a0); a1 = fmaf(o[q][3],woa.w,a1);
        a0 = fmaf(o[q][4],wob.x,a0); a1 = fmaf(o[q][5],wob.y,a1);
        a0 = fmaf(o[q][6],wob.z,a0); a1 = fmaf(o[q][7],wob.w,a1);
        esum += sigmoidf_(a0+a1);
    }

    // ebond partial: sum over ALL bonds (duplicates included)
    float ev = -Desi*esum;
    #pragma unroll
    for(int o2=32;o2>0;o2>>=1) ev += __shfl_down(ev, o2, 64);
    if((tid & 63) == 0) s_part[tid>>6] = ev;
    __syncthreads();   // also completes all LDS accumulator adds (lgkmcnt)
    if(tid==0) atomicAdd(&ebond_acc[b], s_part[0]+s_part[1]+s_part[2]+s_part[3]);

    // flush LDS accumulators -> global (6 atomics/thread)
    float* Db = Delta    + (size_t)b*NATOMS;
    float* Pb = Delta_pi + (size_t)b*NATOMS;
    float* Sb = SO       + (size_t)b*NATOMS;
    for(int n=tid; n<NATOMS; n+=256){
        atomicAdd(&Db[n], accD[n]);
        atomicAdd(&Pb[n], accP[n]);
        atomicAdd(&Sb[n], accS[n]);
    }

    // ticket: barrier drains this block's vmcnt -> all its device-scope
    // atomics performed. No fence (R6-proven).
    __syncthreads();
    if(tid==0) s_rank = atomicAdd(&done[b], 1u);
    __syncthreads();
    if(s_rank != BPB-1) return;

    // ---- tail block (last to finish for this batch): atom phase ----
    float lp1=gp[0], ovun3=gp[1], ovun4=gp[2], ovun6=gp[3], ovun7=gp[4], ovun8=gp[5];
    float acc = 0.f;
    for(int n=tid; n<NATOMS; n+=256){
        int s = spec[n];
        const float* pa = sp_p + s*5;
        float val=pa[0], vale=pa[1], lp2=pa[2], ovun2=pa[3], ovun5=pa[4];
        size_t idx = (size_t)b*NATOMS + n;
        float D   = __hip_atomic_load(&Delta[idx],    __ATOMIC_RELAXED, __HIP_MEMORY_SCOPE_AGENT);
        float Dpi = __hip_atomic_load(&Delta_pi[idx], __ATOMIC_RELAXED, __HIP_MEMORY_SCOPE_AGENT);
        float so  = __hip_atomic_load(&SO[idx],       __ATOMIC_RELAXED, __HIP_MEMORY_SCOPE_AGENT);

        float Nlp = 0.5f*(vale-val);
        float de  = 0.5f*(D-vale);
        float De  = fminf(ceilf(de), 0.f);          // -relu(-ceil(x)) == min(ceil(x),0)
        float t   = 1.f + de - De;
        float nlp = -De + __expf(-lp1*4.f*t*t);
        float Dlp = fmaxf(Nlp - nlp + 1.f, 0.f) - 1.f;
        float Elone = lp2*Dlp/(1.f+__expf(-75.f*Dlp));
        float dlp = D - val - Dlp/(1.f + ovun3*__expf(ovun4*Dpi));
        float denom = dlp + val;
        float otrm1 = 1.f/((denom!=0.f)?denom:1e-8f);
        float Eover = so*otrm1*dlp*sigmoidf_(-ovun2*dlp);
        float Eunder = -ovun5*(1.f-__expf(ovun6*dlp))*sigmoidf_(ovun2*dlp)
                       /(1.f + ovun7*__expf(ovun8*Dpi));
        acc += Elone + Eover + Eunder;
    }
    #pragma unroll
    for(int o2=32;o2>0;o2>>=1) acc += __shfl_down(acc, o2, 64);
    __syncthreads();                          // s_part reuse
    if((tid & 63) == 0) s_part[tid>>6] = acc;
    __syncthreads();
    if(tid==0){
        float eb = __hip_atomic_load(&ebond_acc[b], __ATOMIC_RELAXED, __HIP_MEMORY_SCOPE_AGENT);
        out[b] = eb + s_part[0]+s_part[1]+s_part[2]+s_part[3];   // sole writer
    }
}

extern "C" void kernel_launch(void* const* d_in, const int* in_sizes, int n_in,
                              void* d_out, int out_size, void* d_ws, size_t ws_size,
                              hipStream_t stream)
{
    const float* x     = (const float*)d_in[0];
    const float* cell  = (const float*)d_in[1];
    const float* rcell = (const float*)d_in[2];
    const float* sp_p  = (const float*)d_in[3];
    const float* gp    = (const float*)d_in[4];
    const float* bp    = (const float*)d_in[5];
    const float* fe_wi = (const float*)d_in[6];
    const float* fe_w  = (const float*)d_in[7];
    const float* fe_b  = (const float*)d_in[8];
    const float* fe_wo = (const float*)d_in[9];
    const float* fe_bo = (const float*)d_in[10];
    const int*   bdid  = (const int*)d_in[11];
    const int*   spec  = (const int*)d_in[12];
    float* out = (float*)d_out;

    // ws layout (zeroed region first, then ownerf which is overwritten):
    // Delta | Delta_pi | SO | ebond_acc | done | bits | ownerf
    float* Delta     = (float*)d_ws;
    float* Delta_pi  = Delta + BATCH*NATOMS;
    float* SO        = Delta_pi + BATCH*NATOMS;
    float* ebond_acc = SO + BATCH*NATOMS;
    unsigned* done   = (unsigned*)(ebond_acc + BATCH);
    unsigned* bits   = done + BATCH;          // BITS_W words (32 KB), single copy
    float* ownerf    = (float*)(bits + BITS_W);

    size_t zbytes = (size_t)(3*BATCH*NATOMS + BATCH)*sizeof(float)
                  + (size_t)BATCH*sizeof(unsigned)
                  + (size_t)BITS_W*sizeof(unsigned);
    hipMemsetAsync(d_ws, 0, zbytes, stream);
    hipMemsetAsync(out, 0, BATCH*sizeof(float), stream);

    claim_kernel<<<dim3(NBONDS/256), 256, 0, stream>>>(bdid, bits, ownerf);
    fused_kernel<<<dim3(BPB, BATCH), 256, 0, stream>>>(
        x, cell, rcell, sp_p, gp, bp, fe_wi, fe_w, fe_b, fe_wo, fe_bo,
        bdid, spec, ownerf, Delta, Delta_pi, SO, ebond_acc, done, out);
}

// Round 10
// 110.865 us; speedup vs baseline: 1.3117x; 1.0089x over previous
//
#include <hip/hip_runtime.h>

#define BATCH 50
#define NATOMS 512
#define NBONDS 4096
#define NXF (NATOMS*3)            // floats of x per batch = 1536 (6 KB)
#define ILP 2                     // bonds per thread (R9-proven sweet spot)
#define BPB (NBONDS/(256*ILP))    // bond blocks per batch = 8
#define BITS_W (NATOMS*NATOMS/32) // pair bitmask words = 8192 (32 KB, in LDS)

__device__ __forceinline__ float sigmoidf_(float x){ return 1.f/(1.f+__expf(-x)); }

// exact transcription of reference _taper
__device__ __forceinline__ float taperf_(float r, float rmin, float rmax){
    float r3  = (r > rmax) ? 1.f : 0.f;
    bool  ok  = (r <= rmax) && (r > rmin);
    float r2  = ok ? r   : 0.f;
    float r20 = ok ? 1.f : 0.f;
    float d   = rmin - rmax;
    float rterm = 1.f/(d*d*d);
    float rm  = rmin*r20;
    float rd  = rm - r2;
    float trm1 = rm + 2.f*r2 - 3.f*rmax*r20;
    return rterm*rd*rd*trm1 + r3;
}

// Single-block claim: ownership bit-table lives in LDS (32 KB) -> no global
// bits array, no memset node. Ownership is batch-independent (bdid shared by
// all batches); exactly one duplicate of each (i,j) wins; duplicates carry
// bit-identical bond values so count-once is exact. Also zeroes done[]
// (poison-safe: harness re-poisons ws every iteration).
__global__ __launch_bounds__(1024) void claim_kernel(const int* __restrict__ bdid,
                                                     float* __restrict__ ownerf,
                                                     unsigned* __restrict__ done){
    __shared__ unsigned bits[BITS_W];
    int tid = threadIdx.x;
    for(int t=tid; t<BITS_W; t+=1024) bits[t] = 0u;
    if(tid < BATCH) done[tid] = 0u;
    __syncthreads();
    for(int k=tid; k<NBONDS; k+=1024){
        int2 ij = ((const int2*)bdid)[k];
        unsigned pidx = (unsigned)(ij.x*NATOMS + ij.y);
        unsigned old = atomicOr(&bits[pidx>>5], 1u<<(pidx&31));
        ownerf[k] = ((old>>(pidx&31)) & 1u) ? 0.f : 1.f;
    }
}

// Fused bond+tail kernel, ILP=2, 400 blocks (R9 config). Cross-block
// aggregation via PER-BLOCK SLICES written with agent-scope relaxed stores
// (write-through to the device-coherent point; vmcnt drained by the
// pre-ticket barrier -- mirror of the R6-proven agent-load protocol).
// Every slice slot is written => no zero-init, poison-safe, and the
// ~300K global atomicAdds of the R9 flush are gone.
__global__ __launch_bounds__(256) void fused_kernel(
    const float* __restrict__ x, const float* __restrict__ cell, const float* __restrict__ rcell,
    const float* __restrict__ sp_p, const float* __restrict__ gp, const float* __restrict__ bp,
    const float* __restrict__ fe_wi, const float* __restrict__ fe_w, const float* __restrict__ fe_b,
    const float* __restrict__ fe_wo, const float* __restrict__ fe_bo,
    const int* __restrict__ bdid, const int* __restrict__ spec,
    const float* __restrict__ ownerf,
    float* __restrict__ Dpart, float* __restrict__ Ppart, float* __restrict__ Spart,
    float* __restrict__ epart, unsigned* __restrict__ done,
    float* __restrict__ out)
{
    __shared__ float s_x[NXF];                       // 6 KB coordinates
    __shared__ float accD[NATOMS], accP[NATOMS], accS[NATOMS]; // 6 KB LDS accumulators
    __shared__ __align__(16) float s_w[320];         // [l][u][v] transposed
    __shared__ __align__(16) float s_wo[8];
    __shared__ float s_wi[24], s_bb[40];
    __shared__ float s_part[4];
    __shared__ unsigned s_rank;
    int tid = threadIdx.x;
    int b   = blockIdx.y;

    // coalesced float4 stage of x[b] into LDS (384 float4 / 256 threads)
    const float4* xb4 = (const float4*)(x + (size_t)b*NXF);
    float4* sx4 = (float4*)s_x;
    sx4[tid] = xb4[tid];
    if(tid < NXF/4 - 256) sx4[tid+256] = xb4[tid+256];
    // zero LDS accumulators
    for(int n=tid; n<NATOMS; n+=256){ accD[n]=0.f; accP[n]=0.f; accS[n]=0.f; }
    // weights: transpose [l][v][u] -> [l][u][v] while staging (LOOP: 320>256)
    for(int t=tid; t<320; t+=256){
        int l = t>>6, rr = t&63, v = rr>>3, u = rr&7;
        s_w[(l<<6) + (u<<3) + v] = fe_w[t];
    }
    if(tid < 24) s_wi[tid] = fe_wi[tid];
    if(tid < 40) s_bb[tid] = fe_b[tid];
    if(tid < 8)  s_wo[tid] = fe_wo[tid];
    __syncthreads();

    // wave-uniform params -> scalar loads
    float botol = gp[6];
    float rosi=bp[0], ropi=bp[1], ropp=bp[2];
    float bo1=bp[3], bo2=bp[4], bo3=bp[5], bo4=bp[6], bo5=bp[7], bo6=bp[8], Desi=bp[9];
    float bo_out = fe_bo[0];
    const float* cb = cell  + b*9;
    const float* rb = rcell + b*9;
    float tmax = 2.f*botol;

    int kbase = blockIdx.x*(256*ILP) + tid;
    float o[ILP][8];

    // ---- per-bond: geometry -> LDS scatter -> MLP layer 0 ----
    #pragma unroll
    for(int q=0;q<ILP;q++){
        int k = kbase + q*256;
        float own = ownerf[k];                 // plain load, no branch
        int2 ij = ((const int2*)bdid)[k];
        int i = ij.x, j = ij.y;
        float dx0 = s_x[3*i+0]-s_x[3*j+0];
        float dx1 = s_x[3*i+1]-s_x[3*j+1];
        float dx2 = s_x[3*i+2]-s_x[3*j+2];
        float f0 = dx0*rb[0]+dx1*rb[3]+dx2*rb[6];
        float f1 = dx0*rb[1]+dx1*rb[4]+dx2*rb[7];
        float f2 = dx0*rb[2]+dx1*rb[5]+dx2*rb[8];
        f0 = (f0>0.5f)?f0-1.f:f0; f0 = (f0<-0.5f)?f0+1.f:f0;
        f1 = (f1>0.5f)?f1-1.f:f1; f1 = (f1<-0.5f)?f1+1.f:f1;
        f2 = (f2>0.5f)?f2-1.f:f2; f2 = (f2<-0.5f)?f2+1.f:f2;
        float v0 = f0*cb[0]+f1*cb[3]+f2*cb[6];
        float v1 = f0*cb[1]+f1*cb[4]+f2*cb[7];
        float v2 = f0*cb[2]+f1*cb[5]+f2*cb[8];
        float r = sqrtf(v0*v0+v1*v1+v2*v2);

        float eterm1 = (1.f+botol)*__expf(bo1*__powf(r/rosi, bo2));
        float eterm2 = __expf(bo3*__powf(r/ropi, bo4));
        float eterm3 = __expf(bo5*__powf(r/ropp, bo6));
        float si = taperf_(eterm1, botol, tmax)*(eterm1-botol);
        float pi = taperf_(eterm2, botol, tmax)*eterm2;
        float pp = taperf_(eterm3, botol, tmax)*eterm3;

        // LDS scatter, scaled by ownership (0 adds are harmless)
        float bop = own*(si+pi+pp), dpi = own*(pi+pp), osi = own*si;
        atomicAdd(&accD[i], bop); atomicAdd(&accD[j], bop);
        atomicAdd(&accP[i], dpi); atomicAdd(&accP[j], dpi);
        atomicAdd(&accS[i], osi); atomicAdd(&accS[j], osi);

        // MLP input layer
        #pragma unroll
        for(int u=0;u<8;u++)
            o[q][u] = sigmoidf_(si*s_wi[u] + pi*s_wi[8+u] + pp*s_wi[16+u]);
    }

    // ---- MLP hidden layers, 2 chains interleaved, weights shared ----
    #pragma unroll
    for(int l=0;l<5;l++){
        const float4* wl = (const float4*)(s_w + (l<<6));
        const float*  bl = s_bb + (l<<3);
        float no[ILP][8];
        #pragma unroll
        for(int u=0;u<8;u++){
            float4 wa = wl[2*u], wb = wl[2*u+1];  // uniform ds_read_b128 x2
            #pragma unroll
            for(int q=0;q<ILP;q++){
                float a0 = fmaf(o[q][0],wa.x, bl[u]);
                float a1 = o[q][1]*wa.y;
                a0 = fmaf(o[q][2],wa.z,a0); a1 = fmaf(o[q][3],wa.w,a1);
                a0 = fmaf(o[q][4],wb.x,a0); a1 = fmaf(o[q][5],wb.y,a1);
                a0 = fmaf(o[q][6],wb.z,a0); a1 = fmaf(o[q][7],wb.w,a1);
                no[q][u] = sigmoidf_(a0+a1);
            }
        }
        #pragma unroll
        for(int q=0;q<ILP;q++)
            #pragma unroll
            for(int u=0;u<8;u++) o[q][u]=no[q][u];
    }
    float4 woa = ((const float4*)s_wo)[0], wob = ((const float4*)s_wo)[1];
    float esum = 0.f;
    #pragma unroll
    for(int q=0;q<ILP;q++){
        float a0 = fmaf(o[q][0],woa.x, bo_out);
        float a1 = o[q][1]*woa.y;
        a0 = fmaf(o[q][2],woa.z,a0); a1 = fmaf(o[q][3],woa.w,a1);
        a0 = fmaf(o[q][4],wob.x,a0); a1 = fmaf(o[q][5],wob.y,a1);
        a0 = fmaf(o[q][6],wob.z,a0); a1 = fmaf(o[q][7],wob.w,a1);
        esum += sigmoidf_(a0+a1);
    }

    // ebond partial: sum over ALL bonds (duplicates included)
    float ev = -Desi*esum;
    #pragma unroll
    for(int o2=32;o2>0;o2>>=1) ev += __shfl_down(ev, o2, 64);
    if((tid & 63) == 0) s_part[tid>>6] = ev;
    __syncthreads();   // also completes all LDS accumulator adds (lgkmcnt)

    // flush LDS accumulators + ebond partial -> per-block slices.
    // Agent-scope relaxed stores: write through to the device-coherent point.
    size_t sl = ((size_t)b*BPB + blockIdx.x)*NATOMS;
    for(int n=tid; n<NATOMS; n+=256){
        __hip_atomic_store(&Dpart[sl+n], accD[n], __ATOMIC_RELAXED, __HIP_MEMORY_SCOPE_AGENT);
        __hip_atomic_store(&Ppart[sl+n], accP[n], __ATOMIC_RELAXED, __HIP_MEMORY_SCOPE_AGENT);
        __hip_atomic_store(&Spart[sl+n], accS[n], __ATOMIC_RELAXED, __HIP_MEMORY_SCOPE_AGENT);
    }
    if(tid==0)
        __hip_atomic_store(&epart[b*BPB + blockIdx.x],
                           s_part[0]+s_part[1]+s_part[2]+s_part[3],
                           __ATOMIC_RELAXED, __HIP_MEMORY_SCOPE_AGENT);

    // ticket: barrier drains this block's vmcnt -> all slice stores are at
    // the coherent point before the ticket is taken. No fence (R6-proven).
    __syncthreads();
    if(tid==0) s_rank = atomicAdd(&done[b], 1u);
    __syncthreads();
    if(s_rank != BPB-1) return;

    // ---- tail block (last to finish for this batch): atom phase ----
    float lp1=gp[0], ovun3=gp[1], ovun4=gp[2], ovun6=gp[3], ovun7=gp[4], ovun8=gp[5];
    float acc = 0.f;
    for(int n=tid; n<NATOMS; n+=256){
        // sum the 8 block slices (agent loads: read through coherent point)
        float D=0.f, Dpi=0.f, so=0.f;
        size_t base = (size_t)b*BPB*NATOMS + n;
        #pragma unroll
        for(int blk=0; blk<BPB; blk++){
            size_t idx = base + (size_t)blk*NATOMS;
            D   += __hip_atomic_load(&Dpart[idx], __ATOMIC_RELAXED, __HIP_MEMORY_SCOPE_AGENT);
            Dpi += __hip_atomic_load(&Ppart[idx], __ATOMIC_RELAXED, __HIP_MEMORY_SCOPE_AGENT);
            so  += __hip_atomic_load(&Spart[idx], __ATOMIC_RELAXED, __HIP_MEMORY_SCOPE_AGENT);
        }
        int s = spec[n];
        const float* pa = sp_p + s*5;
        float val=pa[0], vale=pa[1], lp2=pa[2], ovun2=pa[3], ovun5=pa[4];

        float Nlp = 0.5f*(vale-val);
        float de  = 0.5f*(D-vale);
        float De  = fminf(ceilf(de), 0.f);          // -relu(-ceil(x)) == min(ceil(x),0)
        float t   = 1.f + de - De;
        float nlp = -De + __expf(-lp1*4.f*t*t);
        float Dlp = fmaxf(Nlp - nlp + 1.f, 0.f) - 1.f;
        float Elone = lp2*Dlp/(1.f+__expf(-75.f*Dlp));
        float dlp = D - val - Dlp/(1.f + ovun3*__expf(ovun4*Dpi));
        float denom = dlp + val;
        float otrm1 = 1.f/((denom!=0.f)?denom:1e-8f);
        float Eover = so*otrm1*dlp*sigmoidf_(-ovun2*dlp);
        float Eunder = -ovun5*(1.f-__expf(ovun6*dlp))*sigmoidf_(ovun2*dlp)
                       /(1.f + ovun7*__expf(ovun8*Dpi));
        acc += Elone + Eover + Eunder;
    }
    #pragma unroll
    for(int o2=32;o2>0;o2>>=1) acc += __shfl_down(acc, o2, 64);
    __syncthreads();                          // s_part reuse
    if((tid & 63) == 0) s_part[tid>>6] = acc;
    __syncthreads();
    if(tid==0){
        float eb = 0.f;
        #pragma unroll
        for(int blk=0; blk<BPB; blk++)
            eb += __hip_atomic_load(&epart[b*BPB + blk], __ATOMIC_RELAXED, __HIP_MEMORY_SCOPE_AGENT);
        out[b] = eb + s_part[0]+s_part[1]+s_part[2]+s_part[3];   // sole writer
    }
}

extern "C" void kernel_launch(void* const* d_in, const int* in_sizes, int n_in,
                              void* d_out, int out_size, void* d_ws, size_t ws_size,
                              hipStream_t stream)
{
    const float* x     = (const float*)d_in[0];
    const float* cell  = (const float*)d_in[1];
    const float* rcell = (const float*)d_in[2];
    const float* sp_p  = (const float*)d_in[3];
    const float* gp    = (const float*)d_in[4];
    const float* bp    = (const float*)d_in[5];
    const float* fe_wi = (const float*)d_in[6];
    const float* fe_w  = (const float*)d_in[7];
    const float* fe_b  = (const float*)d_in[8];
    const float* fe_wo = (const float*)d_in[9];
    const float* fe_bo = (const float*)d_in[10];
    const int*   bdid  = (const int*)d_in[11];
    const int*   spec  = (const int*)d_in[12];
    float* out = (float*)d_out;

    // ws layout -- NOTHING needs zero-init (poison-safe by construction):
    // Dpart | Ppart | Spart  : [BATCH][BPB][NATOMS], every slot stored
    // epart                  : [BATCH][BPB], every slot stored
    // done                   : [BATCH], zeroed by claim_kernel
    // ownerf                 : [NBONDS], fully written by claim_kernel
    float* Dpart  = (float*)d_ws;
    float* Ppart  = Dpart + (size_t)BATCH*BPB*NATOMS;
    float* Spart  = Ppart + (size_t)BATCH*BPB*NATOMS;
    float* epart  = Spart + (size_t)BATCH*BPB*NATOMS;
    unsigned* done = (unsigned*)(epart + BATCH*BPB);
    float* ownerf  = (float*)(done + BATCH);

    claim_kernel<<<dim3(1), 1024, 0, stream>>>(bdid, ownerf, done);
    fused_kernel<<<dim3(BPB, BATCH), 256, 0, stream>>>(
        x, cell, rcell, sp_p, gp, bp, fe_wi, fe_w, fe_b, fe_wo, fe_bo,
        bdid, spec, ownerf, Dpart, Ppart, Spart, epart, done, out);
}

// Round 11
// 108.141 us; speedup vs baseline: 1.3448x; 1.0252x over previous
//
#include <hip/hip_runtime.h>

#define BATCH 50
#define NATOMS 512
#define NBONDS 4096
#define NXF (NATOMS*3)            // floats of x per batch = 1536 (6 KB)
#define ILP 2                     // bonds per thread (R9/R10-proven sweet spot)
#define BPB (NBONDS/(256*ILP))    // bond blocks per batch = 8
#define BITS_W (NATOMS*NATOMS/32) // pair bitmask words = 8192 (32 KB, in LDS)

__device__ __forceinline__ float sigmoidf_(float x){ return 1.f/(1.f+__expf(-x)); }

// exact transcription of reference _taper
__device__ __forceinline__ float taperf_(float r, float rmin, float rmax){
    float r3  = (r > rmax) ? 1.f : 0.f;
    bool  ok  = (r <= rmax) && (r > rmin);
    float r2  = ok ? r   : 0.f;
    float r20 = ok ? 1.f : 0.f;
    float d   = rmin - rmax;
    float rterm = 1.f/(d*d*d);
    float rm  = rmin*r20;
    float rd  = rm - r2;
    float trm1 = rm + 2.f*r2 - 3.f*rmax*r20;
    return rterm*rd*rd*trm1 + r3;
}

// Single-block claim: ownership bit-table in LDS (32 KB). Ownership is
// batch-independent (bdid shared by all batches); exactly one duplicate of
// each (i,j) wins; duplicates carry bit-identical bond values so count-once
// is exact regardless of which duplicate wins.
__global__ __launch_bounds__(1024) void claim_kernel(const int* __restrict__ bdid,
                                                     float* __restrict__ ownerf){
    __shared__ unsigned bits[BITS_W];
    int tid = threadIdx.x;
    for(int t=tid; t<BITS_W; t+=1024) bits[t] = 0u;
    __syncthreads();
    for(int k=tid; k<NBONDS; k+=1024){
        int2 ij = ((const int2*)bdid)[k];
        unsigned pidx = (unsigned)(ij.x*NATOMS + ij.y);
        unsigned old = atomicOr(&bits[pidx>>5], 1u<<(pidx&31));
        ownerf[k] = ((old>>(pidx&31)) & 1u) ? 0.f : 1.f;
    }
}

// Bond kernel, ILP=2, 400 blocks (R9/R10 core, unchanged). LDS
// pre-aggregation -> per-block slices via PLAIN coalesced stores: the
// following kernel dispatch on the same stream provides full release/acquire
// (kernel-boundary coherence), so no agent-scope ops, no ticket, no tail.
// Every slice slot is written => poison-safe, no memset anywhere.
__global__ __launch_bounds__(256) void bond_kernel(
    const float* __restrict__ x, const float* __restrict__ cell, const float* __restrict__ rcell,
    const float* __restrict__ gp, const float* __restrict__ bp,
    const float* __restrict__ fe_wi, const float* __restrict__ fe_w, const float* __restrict__ fe_b,
    const float* __restrict__ fe_wo, const float* __restrict__ fe_bo,
    const int* __restrict__ bdid, const float* __restrict__ ownerf,
    float* __restrict__ Dpart, float* __restrict__ Ppart, float* __restrict__ Spart,
    float* __restrict__ epart)
{
    __shared__ float s_x[NXF];                       // 6 KB coordinates
    __shared__ float accD[NATOMS], accP[NATOMS], accS[NATOMS]; // 6 KB LDS accumulators
    __shared__ __align__(16) float s_w[320];         // [l][u][v] transposed
    __shared__ __align__(16) float s_wo[8];
    __shared__ float s_wi[24], s_bb[40];
    __shared__ float s_part[4];
    int tid = threadIdx.x;
    int b   = blockIdx.y;

    // coalesced float4 stage of x[b] into LDS (384 float4 / 256 threads)
    const float4* xb4 = (const float4*)(x + (size_t)b*NXF);
    float4* sx4 = (float4*)s_x;
    sx4[tid] = xb4[tid];
    if(tid < NXF/4 - 256) sx4[tid+256] = xb4[tid+256];
    // zero LDS accumulators
    for(int n=tid; n<NATOMS; n+=256){ accD[n]=0.f; accP[n]=0.f; accS[n]=0.f; }
    // weights: transpose [l][v][u] -> [l][u][v] while staging (LOOP: 320>256)
    for(int t=tid; t<320; t+=256){
        int l = t>>6, rr = t&63, v = rr>>3, u = rr&7;
        s_w[(l<<6) + (u<<3) + v] = fe_w[t];
    }
    if(tid < 24) s_wi[tid] = fe_wi[tid];
    if(tid < 40) s_bb[tid] = fe_b[tid];
    if(tid < 8)  s_wo[tid] = fe_wo[tid];
    __syncthreads();

    // wave-uniform params -> scalar loads
    float botol = gp[6];
    float rosi=bp[0], ropi=bp[1], ropp=bp[2];
    float bo1=bp[3], bo2=bp[4], bo3=bp[5], bo4=bp[6], bo5=bp[7], bo6=bp[8], Desi=bp[9];
    float bo_out = fe_bo[0];
    const float* cb = cell  + b*9;
    const float* rb = rcell + b*9;
    float tmax = 2.f*botol;

    int kbase = blockIdx.x*(256*ILP) + tid;
    float o[ILP][8];

    // ---- per-bond: geometry -> LDS scatter -> MLP layer 0 ----
    #pragma unroll
    for(int q=0;q<ILP;q++){
        int k = kbase + q*256;
        float own = ownerf[k];                 // plain load, no branch
        int2 ij = ((const int2*)bdid)[k];
        int i = ij.x, j = ij.y;
        float dx0 = s_x[3*i+0]-s_x[3*j+0];
        float dx1 = s_x[3*i+1]-s_x[3*j+1];
        float dx2 = s_x[3*i+2]-s_x[3*j+2];
        float f0 = dx0*rb[0]+dx1*rb[3]+dx2*rb[6];
        float f1 = dx0*rb[1]+dx1*rb[4]+dx2*rb[7];
        float f2 = dx0*rb[2]+dx1*rb[5]+dx2*rb[8];
        f0 = (f0>0.5f)?f0-1.f:f0; f0 = (f0<-0.5f)?f0+1.f:f0;
        f1 = (f1>0.5f)?f1-1.f:f1; f1 = (f1<-0.5f)?f1+1.f:f1;
        f2 = (f2>0.5f)?f2-1.f:f2; f2 = (f2<-0.5f)?f2+1.f:f2;
        float v0 = f0*cb[0]+f1*cb[3]+f2*cb[6];
        float v1 = f0*cb[1]+f1*cb[4]+f2*cb[7];
        float v2 = f0*cb[2]+f1*cb[5]+f2*cb[8];
        float r = sqrtf(v0*v0+v1*v1+v2*v2);

        float eterm1 = (1.f+botol)*__expf(bo1*__powf(r/rosi, bo2));
        float eterm2 = __expf(bo3*__powf(r/ropi, bo4));
        float eterm3 = __expf(bo5*__powf(r/ropp, bo6));
        float si = taperf_(eterm1, botol, tmax)*(eterm1-botol);
        float pi = taperf_(eterm2, botol, tmax)*eterm2;
        float pp = taperf_(eterm3, botol, tmax)*eterm3;

        // LDS scatter, scaled by ownership (0 adds are harmless)
        float bop = own*(si+pi+pp), dpi = own*(pi+pp), osi = own*si;
        atomicAdd(&accD[i], bop); atomicAdd(&accD[j], bop);
        atomicAdd(&accP[i], dpi); atomicAdd(&accP[j], dpi);
        atomicAdd(&accS[i], osi); atomicAdd(&accS[j], osi);

        // MLP input layer
        #pragma unroll
        for(int u=0;u<8;u++)
            o[q][u] = sigmoidf_(si*s_wi[u] + pi*s_wi[8+u] + pp*s_wi[16+u]);
    }

    // ---- MLP hidden layers, 2 chains interleaved, weights shared ----
    #pragma unroll
    for(int l=0;l<5;l++){
        const float4* wl = (const float4*)(s_w + (l<<6));
        const float*  bl = s_bb + (l<<3);
        float no[ILP][8];
        #pragma unroll
        for(int u=0;u<8;u++){
            float4 wa = wl[2*u], wb = wl[2*u+1];  // uniform ds_read_b128 x2
            #pragma unroll
            for(int q=0;q<ILP;q++){
                float a0 = fmaf(o[q][0],wa.x, bl[u]);
                float a1 = o[q][1]*wa.y;
                a0 = fmaf(o[q][2],wa.z,a0); a1 = fmaf(o[q][3],wa.w,a1);
                a0 = fmaf(o[q][4],wb.x,a0); a1 = fmaf(o[q][5],wb.y,a1);
                a0 = fmaf(o[q][6],wb.z,a0); a1 = fmaf(o[q][7],wb.w,a1);
                no[q][u] = sigmoidf_(a0+a1);
            }
        }
        #pragma unroll
        for(int q=0;q<ILP;q++)
            #pragma unroll
            for(int u=0;u<8;u++) o[q][u]=no[q][u];
    }
    float4 woa = ((const float4*)s_wo)[0], wob = ((const float4*)s_wo)[1];
    float esum = 0.f;
    #pragma unroll
    for(int q=0;q<ILP;q++){
        float a0 = fmaf(o[q][0],woa.x, bo_out);
        float a1 = o[q][1]*woa.y;
        a0 = fmaf(o[q][2],woa.z,a0); a1 = fmaf(o[q][3],woa.w,a1);
        a0 = fmaf(o[q][4],wob.x,a0); a1 = fmaf(o[q][5],wob.y,a1);
        a0 = fmaf(o[q][6],wob.z,a0); a1 = fmaf(o[q][7],wob.w,a1);
        esum += sigmoidf_(a0+a1);
    }

    // ebond partial: sum over ALL bonds (duplicates included)
    float ev = -Desi*esum;
    #pragma unroll
    for(int o2=32;o2>0;o2>>=1) ev += __shfl_down(ev, o2, 64);
    if((tid & 63) == 0) s_part[tid>>6] = ev;
    __syncthreads();   // also completes all LDS accumulator adds (lgkmcnt)

    // flush LDS accumulators + ebond partial -> per-block slices.
    // PLAIN stores: next dispatch boundary makes them visible device-wide.
    size_t sl = ((size_t)b*BPB + blockIdx.x)*NATOMS;
    for(int n=tid; n<NATOMS; n+=256){
        Dpart[sl+n] = accD[n];
        Ppart[sl+n] = accP[n];
        Spart[sl+n] = accS[n];
    }
    if(tid==0) epart[b*BPB + blockIdx.x] = s_part[0]+s_part[1]+s_part[2]+s_part[3];
}

// Atom kernel: one 512-thread block per batch. Sums the 8 bond-block slices
// (plain coalesced loads -- kernel boundary guarantees visibility), does the
// per-atom energy, block-reduces, single plain store to out[b].
__global__ __launch_bounds__(512) void atom_kernel(
    const float* __restrict__ sp_p, const float* __restrict__ gp,
    const int* __restrict__ spec,
    const float* __restrict__ Dpart, const float* __restrict__ Ppart,
    const float* __restrict__ Spart, const float* __restrict__ epart,
    float* __restrict__ out)
{
    __shared__ float s_red[8];
    int tid = threadIdx.x;      // == atom index n
    int b   = blockIdx.x;
    float lp1=gp[0], ovun3=gp[1], ovun4=gp[2], ovun6=gp[3], ovun7=gp[4], ovun8=gp[5];

    // sum slices
    float D=0.f, Dpi=0.f, so=0.f;
    size_t base = (size_t)b*BPB*NATOMS + tid;
    #pragma unroll
    for(int blk=0; blk<BPB; blk++){
        size_t idx = base + (size_t)blk*NATOMS;
        D   += Dpart[idx];
        Dpi += Ppart[idx];
        so  += Spart[idx];
    }
    int s = spec[tid];
    const float* pa = sp_p + s*5;
    float val=pa[0], vale=pa[1], lp2=pa[2], ovun2=pa[3], ovun5=pa[4];

    float Nlp = 0.5f*(vale-val);
    float de  = 0.5f*(D-vale);
    float De  = fminf(ceilf(de), 0.f);          // -relu(-ceil(x)) == min(ceil(x),0)
    float t   = 1.f + de - De;
    float nlp = -De + __expf(-lp1*4.f*t*t);
    float Dlp = fmaxf(Nlp - nlp + 1.f, 0.f) - 1.f;
    float Elone = lp2*Dlp/(1.f+__expf(-75.f*Dlp));
    float dlp = D - val - Dlp/(1.f + ovun3*__expf(ovun4*Dpi));
    float denom = dlp + val;
    float otrm1 = 1.f/((denom!=0.f)?denom:1e-8f);
    float Eover = so*otrm1*dlp*sigmoidf_(-ovun2*dlp);
    float Eunder = -ovun5*(1.f-__expf(ovun6*dlp))*sigmoidf_(ovun2*dlp)
                   /(1.f + ovun7*__expf(ovun8*Dpi));
    float acc = Elone + Eover + Eunder;

    #pragma unroll
    for(int o2=32;o2>0;o2>>=1) acc += __shfl_down(acc, o2, 64);
    if((tid & 63) == 0) s_red[tid>>6] = acc;
    __syncthreads();
    if(tid==0){
        float tot = 0.f;
        #pragma unroll
        for(int w=0;w<8;w++) tot += s_red[w];
        #pragma unroll
        for(int blk=0; blk<BPB; blk++) tot += epart[b*BPB + blk];
        out[b] = tot;                              // sole writer, plain store
    }
}

extern "C" void kernel_launch(void* const* d_in, const int* in_sizes, int n_in,
                              void* d_out, int out_size, void* d_ws, size_t ws_size,
                              hipStream_t stream)
{
    const float* x     = (const float*)d_in[0];
    const float* cell  = (const float*)d_in[1];
    const float* rcell = (const float*)d_in[2];
    const float* sp_p  = (const float*)d_in[3];
    const float* gp    = (const float*)d_in[4];
    const float* bp    = (const float*)d_in[5];
    const float* fe_wi = (const float*)d_in[6];
    const float* fe_w  = (const float*)d_in[7];
    const float* fe_b  = (const float*)d_in[8];
    const float* fe_wo = (const float*)d_in[9];
    const float* fe_bo = (const float*)d_in[10];
    const int*   bdid  = (const int*)d_in[11];
    const int*   spec  = (const int*)d_in[12];
    float* out = (float*)d_out;

    // ws layout -- NOTHING needs zero-init (poison-safe by construction):
    // Dpart | Ppart | Spart : [BATCH][BPB][NATOMS], every slot stored by bond
    // epart                 : [BATCH][BPB], every slot stored by bond
    // ownerf                : [NBONDS], fully written by claim
    float* Dpart  = (float*)d_ws;
    float* Ppart  = Dpart + (size_t)BATCH*BPB*NATOMS;
    float* Spart  = Ppart + (size_t)BATCH*BPB*NATOMS;
    float* epart  = Spart + (size_t)BATCH*BPB*NATOMS;
    float* ownerf = epart + BATCH*BPB;

    claim_kernel<<<dim3(1), 1024, 0, stream>>>(bdid, ownerf);
    bond_kernel<<<dim3(BPB, BATCH), 256, 0, stream>>>(
        x, cell, rcell, gp, bp, fe_wi, fe_w, fe_b, fe_wo, fe_bo,
        bdid, ownerf, Dpart, Ppart, Spart, epart);
    atom_kernel<<<dim3(BATCH), 512, 0, stream>>>(
        sp_p, gp, spec, Dpart, Ppart, Spart, epart, out);
}

// Round 12
// 104.989 us; speedup vs baseline: 1.3852x; 1.0300x over previous
//
#include <hip/hip_runtime.h>

#define BATCH 50
#define NATOMS 512
#define NBONDS 4096
#define NXF (NATOMS*3)            // floats of x per batch = 1536 (6 KB)
#define ILP 2                     // bonds per thread (R9/R10/R11-proven)
#define TPB 512                   // coarsened: 512-thread bond blocks
#define BPB (NBONDS/(TPB*ILP))    // bond blocks per batch = 4
#define BITS_W (NATOMS*NATOMS/32) // pair bitmask words = 8192 (32 KB, in LDS)

__device__ __forceinline__ float sigmoidf_(float x){ return 1.f/(1.f+__expf(-x)); }

// exact transcription of reference _taper
__device__ __forceinline__ float taperf_(float r, float rmin, float rmax){
    float r3  = (r > rmax) ? 1.f : 0.f;
    bool  ok  = (r <= rmax) && (r > rmin);
    float r2  = ok ? r   : 0.f;
    float r20 = ok ? 1.f : 0.f;
    float d   = rmin - rmax;
    float rterm = 1.f/(d*d*d);
    float rm  = rmin*r20;
    float rd  = rm - r2;
    float trm1 = rm + 2.f*r2 - 3.f*rmax*r20;
    return rterm*rd*rd*trm1 + r3;
}

// Single-block claim: ownership bit-table in LDS (32 KB). Ownership is
// batch-independent (bdid shared by all batches); exactly one duplicate of
// each (i,j) wins; duplicates carry bit-identical bond values so count-once
// is exact regardless of which duplicate wins.
__global__ __launch_bounds__(1024) void claim_kernel(const int* __restrict__ bdid,
                                                     float* __restrict__ ownerf){
    __shared__ unsigned bits[BITS_W];
    int tid = threadIdx.x;
    for(int t=tid; t<BITS_W; t+=1024) bits[t] = 0u;
    __syncthreads();
    for(int k=tid; k<NBONDS; k+=1024){
        int2 ij = ((const int2*)bdid)[k];
        unsigned pidx = (unsigned)(ij.x*NATOMS + ij.y);
        unsigned old = atomicOr(&bits[pidx>>5], 1u<<(pidx&31));
        ownerf[k] = ((old>>(pidx&31)) & 1u) ? 0.f : 1.f;
    }
}

// Bond kernel: COARSENED to 512 threads (BPB=4, 200 blocks). Same per-thread
// body as R11 (ILP=2, fat codegen, 2 waves/SIMD); staging/barrier/slice
// overhead paid half as often. Plain-store slices; next dispatch boundary
// provides device-wide visibility (R11-proven). Poison-safe: every slot
// written, no memsets anywhere.
__global__ __launch_bounds__(TPB) void bond_kernel(
    const float* __restrict__ x, const float* __restrict__ cell, const float* __restrict__ rcell,
    const float* __restrict__ gp, const float* __restrict__ bp,
    const float* __restrict__ fe_wi, const float* __restrict__ fe_w, const float* __restrict__ fe_b,
    const float* __restrict__ fe_wo, const float* __restrict__ fe_bo,
    const int* __restrict__ bdid, const float* __restrict__ ownerf,
    float* __restrict__ Dpart, float* __restrict__ Ppart, float* __restrict__ Spart,
    float* __restrict__ epart)
{
    __shared__ float s_x[NXF];                       // 6 KB coordinates
    __shared__ float accD[NATOMS], accP[NATOMS], accS[NATOMS]; // 6 KB LDS accumulators
    __shared__ __align__(16) float s_w[320];         // [l][u][v] transposed
    __shared__ __align__(16) float s_wo[8];
    __shared__ float s_wi[24], s_bb[40];
    __shared__ float s_part[TPB/64];
    int tid = threadIdx.x;
    int b   = blockIdx.y;

    // coalesced float4 stage of x[b] into LDS (384 float4 / 512 threads)
    const float4* xb4 = (const float4*)(x + (size_t)b*NXF);
    float4* sx4 = (float4*)s_x;
    if(tid < NXF/4) sx4[tid] = xb4[tid];
    // zero LDS accumulators (512 threads == NATOMS: one store each)
    accD[tid]=0.f; accP[tid]=0.f; accS[tid]=0.f;
    // weights: transpose [l][v][u] -> [l][u][v] while staging (320 < 512)
    if(tid < 320){
        int l = tid>>6, rr = tid&63, v = rr>>3, u = rr&7;
        s_w[(l<<6) + (u<<3) + v] = fe_w[tid];
    }
    if(tid < 24) s_wi[tid] = fe_wi[tid];
    if(tid < 40) s_bb[tid] = fe_b[tid];
    if(tid < 8)  s_wo[tid] = fe_wo[tid];
    __syncthreads();

    // wave-uniform params -> scalar loads
    float botol = gp[6];
    float rosi=bp[0], ropi=bp[1], ropp=bp[2];
    float bo1=bp[3], bo2=bp[4], bo3=bp[5], bo4=bp[6], bo5=bp[7], bo6=bp[8], Desi=bp[9];
    float bo_out = fe_bo[0];
    const float* cb = cell  + b*9;
    const float* rb = rcell + b*9;
    float tmax = 2.f*botol;

    int kbase = blockIdx.x*(TPB*ILP) + tid;
    float o[ILP][8];

    // ---- per-bond: geometry -> LDS scatter -> MLP layer 0 ----
    #pragma unroll
    for(int q=0;q<ILP;q++){
        int k = kbase + q*TPB;
        float own = ownerf[k];                 // plain load, no branch
        int2 ij = ((const int2*)bdid)[k];
        int i = ij.x, j = ij.y;
        float dx0 = s_x[3*i+0]-s_x[3*j+0];
        float dx1 = s_x[3*i+1]-s_x[3*j+1];
        float dx2 = s_x[3*i+2]-s_x[3*j+2];
        float f0 = dx0*rb[0]+dx1*rb[3]+dx2*rb[6];
        float f1 = dx0*rb[1]+dx1*rb[4]+dx2*rb[7];
        float f2 = dx0*rb[2]+dx1*rb[5]+dx2*rb[8];
        f0 = (f0>0.5f)?f0-1.f:f0; f0 = (f0<-0.5f)?f0+1.f:f0;
        f1 = (f1>0.5f)?f1-1.f:f1; f1 = (f1<-0.5f)?f1+1.f:f1;
        f2 = (f2>0.5f)?f2-1.f:f2; f2 = (f2<-0.5f)?f2+1.f:f2;
        float v0 = f0*cb[0]+f1*cb[3]+f2*cb[6];
        float v1 = f0*cb[1]+f1*cb[4]+f2*cb[7];
        float v2 = f0*cb[2]+f1*cb[5]+f2*cb[8];
        float r = sqrtf(v0*v0+v1*v1+v2*v2);

        float eterm1 = (1.f+botol)*__expf(bo1*__powf(r/rosi, bo2));
        float eterm2 = __expf(bo3*__powf(r/ropi, bo4));
        float eterm3 = __expf(bo5*__powf(r/ropp, bo6));
        float si = taperf_(eterm1, botol, tmax)*(eterm1-botol);
        float pi = taperf_(eterm2, botol, tmax)*eterm2;
        float pp = taperf_(eterm3, botol, tmax)*eterm3;

        // LDS scatter, scaled by ownership (0 adds are harmless)
        float bop = own*(si+pi+pp), dpi = own*(pi+pp), osi = own*si;
        atomicAdd(&accD[i], bop); atomicAdd(&accD[j], bop);
        atomicAdd(&accP[i], dpi); atomicAdd(&accP[j], dpi);
        atomicAdd(&accS[i], osi); atomicAdd(&accS[j], osi);

        // MLP input layer
        #pragma unroll
        for(int u=0;u<8;u++)
            o[q][u] = sigmoidf_(si*s_wi[u] + pi*s_wi[8+u] + pp*s_wi[16+u]);
    }

    // ---- MLP hidden layers, 2 chains interleaved, weights shared ----
    #pragma unroll
    for(int l=0;l<5;l++){
        const float4* wl = (const float4*)(s_w + (l<<6));
        const float*  bl = s_bb + (l<<3);
        float no[ILP][8];
        #pragma unroll
        for(int u=0;u<8;u++){
            float4 wa = wl[2*u], wb = wl[2*u+1];  // uniform ds_read_b128 x2
            #pragma unroll
            for(int q=0;q<ILP;q++){
                float a0 = fmaf(o[q][0],wa.x, bl[u]);
                float a1 = o[q][1]*wa.y;
                a0 = fmaf(o[q][2],wa.z,a0); a1 = fmaf(o[q][3],wa.w,a1);
                a0 = fmaf(o[q][4],wb.x,a0); a1 = fmaf(o[q][5],wb.y,a1);
                a0 = fmaf(o[q][6],wb.z,a0); a1 = fmaf(o[q][7],wb.w,a1);
                no[q][u] = sigmoidf_(a0+a1);
            }
        }
        #pragma unroll
        for(int q=0;q<ILP;q++)
            #pragma unroll
            for(int u=0;u<8;u++) o[q][u]=no[q][u];
    }
    float4 woa = ((const float4*)s_wo)[0], wob = ((const float4*)s_wo)[1];
    float esum = 0.f;
    #pragma unroll
    for(int q=0;q<ILP;q++){
        float a0 = fmaf(o[q][0],woa.x, bo_out);
        float a1 = o[q][1]*woa.y;
        a0 = fmaf(o[q][2],woa.z,a0); a1 = fmaf(o[q][3],woa.w,a1);
        a0 = fmaf(o[q][4],wob.x,a0); a1 = fmaf(o[q][5],wob.y,a1);
        a0 = fmaf(o[q][6],wob.z,a0); a1 = fmaf(o[q][7],wob.w,a1);
        esum += sigmoidf_(a0+a1);
    }

    // ebond partial: sum over ALL bonds (duplicates included)
    float ev = -Desi*esum;
    #pragma unroll
    for(int o2=32;o2>0;o2>>=1) ev += __shfl_down(ev, o2, 64);
    if((tid & 63) == 0) s_part[tid>>6] = ev;
    __syncthreads();   // also completes all LDS accumulator adds (lgkmcnt)

    // flush LDS accumulators + ebond partial -> per-block slices.
    // PLAIN stores: next dispatch boundary makes them visible device-wide.
    size_t sl = ((size_t)b*BPB + blockIdx.x)*NATOMS;
    Dpart[sl+tid] = accD[tid];       // 512 threads == NATOMS
    Ppart[sl+tid] = accP[tid];
    Spart[sl+tid] = accS[tid];
    if(tid==0){
        float e = 0.f;
        #pragma unroll
        for(int w=0;w<TPB/64;w++) e += s_part[w];
        epart[b*BPB + blockIdx.x] = e;
    }
}

// Atom kernel: one 512-thread block per batch. Sums the 4 bond-block slices
// (plain coalesced loads -- kernel boundary guarantees visibility), does the
// per-atom energy, block-reduces, single plain store to out[b].
__global__ __launch_bounds__(512) void atom_kernel(
    const float* __restrict__ sp_p, const float* __restrict__ gp,
    const int* __restrict__ spec,
    const float* __restrict__ Dpart, const float* __restrict__ Ppart,
    const float* __restrict__ Spart, const float* __restrict__ epart,
    float* __restrict__ out)
{
    __shared__ float s_red[8];
    int tid = threadIdx.x;      // == atom index n
    int b   = blockIdx.x;
    float lp1=gp[0], ovun3=gp[1], ovun4=gp[2], ovun6=gp[3], ovun7=gp[4], ovun8=gp[5];

    // sum slices
    float D=0.f, Dpi=0.f, so=0.f;
    size_t base = (size_t)b*BPB*NATOMS + tid;
    #pragma unroll
    for(int blk=0; blk<BPB; blk++){
        size_t idx = base + (size_t)blk*NATOMS;
        D   += Dpart[idx];
        Dpi += Ppart[idx];
        so  += Spart[idx];
    }
    int s = spec[tid];
    const float* pa = sp_p + s*5;
    float val=pa[0], vale=pa[1], lp2=pa[2], ovun2=pa[3], ovun5=pa[4];

    float Nlp = 0.5f*(vale-val);
    float de  = 0.5f*(D-vale);
    float De  = fminf(ceilf(de), 0.f);          // -relu(-ceil(x)) == min(ceil(x),0)
    float t   = 1.f + de - De;
    float nlp = -De + __expf(-lp1*4.f*t*t);
    float Dlp = fmaxf(Nlp - nlp + 1.f, 0.f) - 1.f;
    float Elone = lp2*Dlp/(1.f+__expf(-75.f*Dlp));
    float dlp = D - val - Dlp/(1.f + ovun3*__expf(ovun4*Dpi));
    float denom = dlp + val;
    float otrm1 = 1.f/((denom!=0.f)?denom:1e-8f);
    float Eover = so*otrm1*dlp*sigmoidf_(-ovun2*dlp);
    float Eunder = -ovun5*(1.f-__expf(ovun6*dlp))*sigmoidf_(ovun2*dlp)
                   /(1.f + ovun7*__expf(ovun8*Dpi));
    float acc = Elone + Eover + Eunder;

    #pragma unroll
    for(int o2=32;o2>0;o2>>=1) acc += __shfl_down(acc, o2, 64);
    if((tid & 63) == 0) s_red[tid>>6] = acc;
    __syncthreads();
    if(tid==0){
        float tot = 0.f;
        #pragma unroll
        for(int w=0;w<8;w++) tot += s_red[w];
        #pragma unroll
        for(int blk=0; blk<BPB; blk++) tot += epart[b*BPB + blk];
        out[b] = tot;                              // sole writer, plain store
    }
}

extern "C" void kernel_launch(void* const* d_in, const int* in_sizes, int n_in,
                              void* d_out, int out_size, void* d_ws, size_t ws_size,
                              hipStream_t stream)
{
    const float* x     = (const float*)d_in[0];
    const float* cell  = (const float*)d_in[1];
    const float* rcell = (const float*)d_in[2];
    const float* sp_p  = (const float*)d_in[3];
    const float* gp    = (const float*)d_in[4];
    const float* bp    = (const float*)d_in[5];
    const float* fe_wi = (const float*)d_in[6];
    const float* fe_w  = (const float*)d_in[7];
    const float* fe_b  = (const float*)d_in[8];
    const float* fe_wo = (const float*)d_in[9];
    const float* fe_bo = (const float*)d_in[10];
    const int*   bdid  = (const int*)d_in[11];
    const int*   spec  = (const int*)d_in[12];
    float* out = (float*)d_out;

    // ws layout -- NOTHING needs zero-init (poison-safe by construction):
    // Dpart | Ppart | Spart : [BATCH][BPB][NATOMS], every slot stored by bond
    // epart                 : [BATCH][BPB], every slot stored by bond
    // ownerf                : [NBONDS], fully written by claim
    float* Dpart  = (float*)d_ws;
    float* Ppart  = Dpart + (size_t)BATCH*BPB*NATOMS;
    float* Spart  = Ppart + (size_t)BATCH*BPB*NATOMS;
    float* epart  = Spart + (size_t)BATCH*BPB*NATOMS;
    float* ownerf = epart + BATCH*BPB;

    claim_kernel<<<dim3(1), 1024, 0, stream>>>(bdid, ownerf);
    bond_kernel<<<dim3(BPB, BATCH), TPB, 0, stream>>>(
        x, cell, rcell, gp, bp, fe_wi, fe_w, fe_b, fe_wo, fe_bo,
        bdid, ownerf, Dpart, Ppart, Spart, epart);
    atom_kernel<<<dim3(BATCH), 512, 0, stream>>>(
        sp_p, gp, spec, Dpart, Ppart, Spart, epart, out);
}

// Round 14
// 104.519 us; speedup vs baseline: 1.3914x; 1.0045x over previous
//
#include <hip/hip_runtime.h>
#include <math.h>

#define BATCH 50
#define NATOMS 512
#define NBONDS 4096
#define NXF (NATOMS*3)            // floats of x per batch = 1536 (6 KB)
#define ILP 2                     // bonds per thread (R9-R12-proven)
#define TPB 512                   // coarsened bond blocks (R12-proven)
#define BPB (NBONDS/(TPB*ILP))    // bond blocks per batch = 4
#define BITS_W (NATOMS*NATOMS/32) // pair bitmask words = 8192 (32 KB, in LDS)

__device__ __forceinline__ float sigmoidf_(float x){ return 1.f/(1.f+__expf(-x)); }

// exact transcription of reference _taper
__device__ __forceinline__ float taperf_(float r, float rmin, float rmax){
    float r3  = (r > rmax) ? 1.f : 0.f;
    bool  ok  = (r <= rmax) && (r > rmin);
    float r2  = ok ? r   : 0.f;
    float r20 = ok ? 1.f : 0.f;
    float d   = rmin - rmax;
    float rterm = 1.f/(d*d*d);
    float rm  = rmin*r20;
    float rd  = rm - r2;
    float trm1 = rm + 2.f*r2 - 3.f*rmax*r20;
    return rterm*rd*rd*trm1 + r3;
}

// Single-block claim: ownership bit-table in LDS (32 KB). Ownership is
// batch-independent (bdid shared by all batches); exactly one duplicate of
// each (i,j) wins; duplicates carry bit-identical bond values so count-once
// is exact regardless of which duplicate wins.
__global__ __launch_bounds__(1024) void claim_kernel(const int* __restrict__ bdid,
                                                     float* __restrict__ ownerf){
    __shared__ unsigned bits[BITS_W];
    int tid = threadIdx.x;
    for(int t=tid; t<BITS_W; t+=1024) bits[t] = 0u;
    __syncthreads();
    for(int k=tid; k<NBONDS; k+=1024){
        int2 ij = ((const int2*)bdid)[k];
        unsigned pidx = (unsigned)(ij.x*NATOMS + ij.y);
        unsigned old = atomicOr(&bits[pidx>>5], 1u<<(pidx&31));
        ownerf[k] = ((old>>(pidx&31)) & 1u) ? 0.f : 1.f;
    }
}

// Bond kernel (R12 structure). Geometry transcendentals restructured in
// NATURAL log (only proven HIP intrinsics __logf/__expf; __exp2f does not
// exist in HIP -- R13 compile failure):
//   r only feeds the three powers; (r/c)^e = __expf(e*(0.5*ln(r2) - ln c))
// -> NO sqrt, ONE __logf, each power = fma+__expf. Per bond:
// sqrt + 3 __powf(=log+exp) + 3 __expf  ->  1 __logf + 6 __expf.
__global__ __launch_bounds__(TPB) void bond_kernel(
    const float* __restrict__ x, const float* __restrict__ cell, const float* __restrict__ rcell,
    const float* __restrict__ gp, const float* __restrict__ bp,
    const float* __restrict__ fe_wi, const float* __restrict__ fe_w, const float* __restrict__ fe_b,
    const float* __restrict__ fe_wo, const float* __restrict__ fe_bo,
    const int* __restrict__ bdid, const float* __restrict__ ownerf,
    float* __restrict__ Dpart, float* __restrict__ Ppart, float* __restrict__ Spart,
    float* __restrict__ epart)
{
    __shared__ float s_x[NXF];                       // 6 KB coordinates
    __shared__ float accD[NATOMS], accP[NATOMS], accS[NATOMS]; // 6 KB LDS accumulators
    __shared__ __align__(16) float s_w[320];         // [l][u][v] transposed
    __shared__ __align__(16) float s_wo[8];
    __shared__ float s_wi[24], s_bb[40];
    __shared__ float s_part[TPB/64];
    int tid = threadIdx.x;
    int b   = blockIdx.y;

    // coalesced float4 stage of x[b] into LDS (384 float4 / 512 threads)
    const float4* xb4 = (const float4*)(x + (size_t)b*NXF);
    float4* sx4 = (float4*)s_x;
    if(tid < NXF/4) sx4[tid] = xb4[tid];
    // zero LDS accumulators (512 threads == NATOMS: one store each)
    accD[tid]=0.f; accP[tid]=0.f; accS[tid]=0.f;
    // weights: transpose [l][v][u] -> [l][u][v] while staging (320 < 512)
    if(tid < 320){
        int l = tid>>6, rr = tid&63, v = rr>>3, u = rr&7;
        s_w[(l<<6) + (u<<3) + v] = fe_w[tid];
    }
    if(tid < 24) s_wi[tid] = fe_wi[tid];
    if(tid < 40) s_bb[tid] = fe_b[tid];
    if(tid < 8)  s_wo[tid] = fe_wo[tid];
    __syncthreads();

    // wave-uniform params -> scalar loads
    float botol = gp[6];
    float rosi=bp[0], ropi=bp[1], ropp=bp[2];
    float bo1=bp[3], bo2=bp[4], bo3=bp[5], bo4=bp[6], bo5=bp[7], bo6=bp[8], Desi=bp[9];
    float bo_out = fe_bo[0];
    const float* cb = cell  + b*9;
    const float* rb = rcell + b*9;
    float tmax = 2.f*botol;
    // per-term power constants: (r/c)^e = __expf(he*lnr2 + ae), lnr2 = ln(r^2)
    float h1 = 0.5f*bo2, a1 = -bo2*logf(rosi);
    float h2 = 0.5f*bo4, a2 = -bo4*logf(ropi);
    float h3 = 0.5f*bo6, a3 = -bo6*logf(ropp);

    int kbase = blockIdx.x*(TPB*ILP) + tid;
    float o[ILP][8];

    // ---- per-bond: geometry -> LDS scatter -> MLP layer 0 ----
    #pragma unroll
    for(int q=0;q<ILP;q++){
        int k = kbase + q*TPB;
        float own = ownerf[k];                 // plain load, no branch
        int2 ij = ((const int2*)bdid)[k];
        int i = ij.x, j = ij.y;
        float dx0 = s_x[3*i+0]-s_x[3*j+0];
        float dx1 = s_x[3*i+1]-s_x[3*j+1];
        float dx2 = s_x[3*i+2]-s_x[3*j+2];
        float f0 = dx0*rb[0]+dx1*rb[3]+dx2*rb[6];
        float f1 = dx0*rb[1]+dx1*rb[4]+dx2*rb[7];
        float f2 = dx0*rb[2]+dx1*rb[5]+dx2*rb[8];
        f0 = (f0>0.5f)?f0-1.f:f0; f0 = (f0<-0.5f)?f0+1.f:f0;
        f1 = (f1>0.5f)?f1-1.f:f1; f1 = (f1<-0.5f)?f1+1.f:f1;
        f2 = (f2>0.5f)?f2-1.f:f2; f2 = (f2<-0.5f)?f2+1.f:f2;
        float v0 = f0*cb[0]+f1*cb[3]+f2*cb[6];
        float v1 = f0*cb[1]+f1*cb[4]+f2*cb[7];
        float v2 = f0*cb[2]+f1*cb[5]+f2*cb[8];
        float r2 = v0*v0+v1*v1+v2*v2;

        // no sqrt: one __logf, three fma+__expf powers, three __expf exps
        float lnr2 = __logf(r2);
        float p1 = __expf(fmaf(h1, lnr2, a1));   // (r/rosi)^bo2
        float p2 = __expf(fmaf(h2, lnr2, a2));   // (r/ropi)^bo4
        float p3 = __expf(fmaf(h3, lnr2, a3));   // (r/ropp)^bo6
        float eterm1 = (1.f+botol)*__expf(bo1*p1);
        float eterm2 = __expf(bo3*p2);
        float eterm3 = __expf(bo5*p3);
        float si = taperf_(eterm1, botol, tmax)*(eterm1-botol);
        float pi = taperf_(eterm2, botol, tmax)*eterm2;
        float pp = taperf_(eterm3, botol, tmax)*eterm3;

        // LDS scatter, scaled by ownership (0 adds are harmless)
        float bop = own*(si+pi+pp), dpi = own*(pi+pp), osi = own*si;
        atomicAdd(&accD[i], bop); atomicAdd(&accD[j], bop);
        atomicAdd(&accP[i], dpi); atomicAdd(&accP[j], dpi);
        atomicAdd(&accS[i], osi); atomicAdd(&accS[j], osi);

        // MLP input layer
        #pragma unroll
        for(int u=0;u<8;u++)
            o[q][u] = sigmoidf_(si*s_wi[u] + pi*s_wi[8+u] + pp*s_wi[16+u]);
    }

    // ---- MLP hidden layers, 2 chains interleaved, weights shared ----
    #pragma unroll
    for(int l=0;l<5;l++){
        const float4* wl = (const float4*)(s_w + (l<<6));
        const float*  bl = s_bb + (l<<3);
        float no[ILP][8];
        #pragma unroll
        for(int u=0;u<8;u++){
            float4 wa = wl[2*u], wb = wl[2*u+1];  // uniform ds_read_b128 x2
            #pragma unroll
            for(int q=0;q<ILP;q++){
                float a0 = fmaf(o[q][0],wa.x, bl[u]);
                float a1v = o[q][1]*wa.y;
                a0 = fmaf(o[q][2],wa.z,a0); a1v = fmaf(o[q][3],wa.w,a1v);
                a0 = fmaf(o[q][4],wb.x,a0); a1v = fmaf(o[q][5],wb.y,a1v);
                a0 = fmaf(o[q][6],wb.z,a0); a1v = fmaf(o[q][7],wb.w,a1v);
                no[q][u] = sigmoidf_(a0+a1v);
            }
        }
        #pragma unroll
        for(int q=0;q<ILP;q++)
            #pragma unroll
            for(int u=0;u<8;u++) o[q][u]=no[q][u];
    }
    float4 woa = ((const float4*)s_wo)[0], wob = ((const float4*)s_wo)[1];
    float esum = 0.f;
    #pragma unroll
    for(int q=0;q<ILP;q++){
        float a0 = fmaf(o[q][0],woa.x, bo_out);
        float a1v = o[q][1]*woa.y;
        a0 = fmaf(o[q][2],woa.z,a0); a1v = fmaf(o[q][3],woa.w,a1v);
        a0 = fmaf(o[q][4],wob.x,a0); a1v = fmaf(o[q][5],wob.y,a1v);
        a0 = fmaf(o[q][6],wob.z,a0); a1v = fmaf(o[q][7],wob.w,a1v);
        esum += sigmoidf_(a0+a1v);
    }

    // ebond partial: sum over ALL bonds (duplicates included)
    float ev = -Desi*esum;
    #pragma unroll
    for(int o2=32;o2>0;o2>>=1) ev += __shfl_down(ev, o2, 64);
    if((tid & 63) == 0) s_part[tid>>6] = ev;
    __syncthreads();   // also completes all LDS accumulator adds (lgkmcnt)

    // flush LDS accumulators + ebond partial -> per-block slices.
    // PLAIN stores: next dispatch boundary makes them visible device-wide.
    size_t sl = ((size_t)b*BPB + blockIdx.x)*NATOMS;
    Dpart[sl+tid] = accD[tid];       // 512 threads == NATOMS
    Ppart[sl+tid] = accP[tid];
    Spart[sl+tid] = accS[tid];
    if(tid==0){
        float e = 0.f;
        #pragma unroll
        for(int w=0;w<TPB/64;w++) e += s_part[w];
        epart[b*BPB + blockIdx.x] = e;
    }
}

// Atom kernel: one 512-thread block per batch. Sums the 4 bond-block slices
// (plain coalesced loads -- kernel boundary guarantees visibility), does the
// per-atom energy, block-reduces, single plain store to out[b].
__global__ __launch_bounds__(512) void atom_kernel(
    const float* __restrict__ sp_p, const float* __restrict__ gp,
    const int* __restrict__ spec,
    const float* __restrict__ Dpart, const float* __restrict__ Ppart,
    const float* __restrict__ Spart, const float* __restrict__ epart,
    float* __restrict__ out)
{
    __shared__ float s_red[8];
    int tid = threadIdx.x;      // == atom index n
    int b   = blockIdx.x;
    float lp1=gp[0], ovun3=gp[1], ovun4=gp[2], ovun6=gp[3], ovun7=gp[4], ovun8=gp[5];

    // sum slices
    float D=0.f, Dpi=0.f, so=0.f;
    size_t base = (size_t)b*BPB*NATOMS + tid;
    #pragma unroll
    for(int blk=0; blk<BPB; blk++){
        size_t idx = base + (size_t)blk*NATOMS;
        D   += Dpart[idx];
        Dpi += Ppart[idx];
        so  += Spart[idx];
    }
    int s = spec[tid];
    const float* pa = sp_p + s*5;
    float val=pa[0], vale=pa[1], lp2=pa[2], ovun2=pa[3], ovun5=pa[4];

    float Nlp = 0.5f*(vale-val);
    float de  = 0.5f*(D-vale);
    float De  = fminf(ceilf(de), 0.f);          // -relu(-ceil(x)) == min(ceil(x),0)
    float t   = 1.f + de - De;
    float nlp = -De + __expf(-lp1*4.f*t*t);
    float Dlp = fmaxf(Nlp - nlp + 1.f, 0.f) - 1.f;
    float Elone = lp2*Dlp/(1.f+__expf(-75.f*Dlp));
    float dlp = D - val - Dlp/(1.f + ovun3*__expf(ovun4*Dpi));
    float denom = dlp + val;
    float otrm1 = 1.f/((denom!=0.f)?denom:1e-8f);
    float Eover = so*otrm1*dlp*sigmoidf_(-ovun2*dlp);
    float Eunder = -ovun5*(1.f-__expf(ovun6*dlp))*sigmoidf_(ovun2*dlp)
                   /(1.f + ovun7*__expf(ovun8*Dpi));
    float acc = Elone + Eover + Eunder;

    #pragma unroll
    for(int o2=32;o2>0;o2>>=1) acc += __shfl_down(acc, o2, 64);
    if((tid & 63) == 0) s_red[tid>>6] = acc;
    __syncthreads();
    if(tid==0){
        float tot = 0.f;
        #pragma unroll
        for(int w=0;w<8;w++) tot += s_red[w];
        #pragma unroll
        for(int blk=0; blk<BPB; blk++) tot += epart[b*BPB + blk];
        out[b] = tot;                              // sole writer, plain store
    }
}

extern "C" void kernel_launch(void* const* d_in, const int* in_sizes, int n_in,
                              void* d_out, int out_size, void* d_ws, size_t ws_size,
                              hipStream_t stream)
{
    const float* x     = (const float*)d_in[0];
    const float* cell  = (const float*)d_in[1];
    const float* rcell = (const float*)d_in[2];
    const float* sp_p  = (const float*)d_in[3];
    const float* gp    = (const float*)d_in[4];
    const float* bp    = (const float*)d_in[5];
    const float* fe_wi = (const float*)d_in[6];
    const float* fe_w  = (const float*)d_in[7];
    const float* fe_b  = (const float*)d_in[8];
    const float* fe_wo = (const float*)d_in[9];
    const float* fe_bo = (const float*)d_in[10];
    const int*   bdid  = (const int*)d_in[11];
    const int*   spec  = (const int*)d_in[12];
    float* out = (float*)d_out;

    // ws layout -- NOTHING needs zero-init (poison-safe by construction):
    // Dpart | Ppart | Spart : [BATCH][BPB][NATOMS], every slot stored by bond
    // epart                 : [BATCH][BPB], every slot stored by bond
    // ownerf                : [NBONDS], fully written by claim
    float* Dpart  = (float*)d_ws;
    float* Ppart  = Dpart + (size_t)BATCH*BPB*NATOMS;
    float* Spart  = Ppart + (size_t)BATCH*BPB*NATOMS;
    float* epart  = Spart + (size_t)BATCH*BPB*NATOMS;
    float* ownerf = epart + BATCH*BPB;

    claim_kernel<<<dim3(1), 1024, 0, stream>>>(bdid, ownerf);
    bond_kernel<<<dim3(BPB, BATCH), TPB, 0, stream>>>(
        x, cell, rcell, gp, bp, fe_wi, fe_w, fe_b, fe_wo, fe_bo,
        bdid, ownerf, Dpart, Ppart, Spart, epart);
    atom_kernel<<<dim3(BATCH), 512, 0, stream>>>(
        sp_p, gp, spec, Dpart, Ppart, Spart, epart, out);
}